// Round 11
// baseline (190.852 us; speedup 1.0000x reference)
//
#include <hip/hip_runtime.h>
#include <hip/hip_bf16.h>

typedef __attribute__((ext_vector_type(8))) short bf16x8;
typedef __attribute__((ext_vector_type(4))) float f32x4;
typedef __attribute__((ext_vector_type(2))) float f32x2;

#define BSH 9       // nodes per bucket = 512
#define BCAP 12288  // per-bucket pair capacity (mean 8163, std ~90)

#if __has_builtin(__builtin_amdgcn_cvt_pk_f32_fp8) && __has_builtin(__builtin_amdgcn_cvt_pk_fp8_f32)
#define FP8_HW 1
#else
#define FP8_HW 0
#endif

// ---------- helpers ----------
__device__ __forceinline__ float bf2f(unsigned short u) {
    return __uint_as_float(((unsigned int)u) << 16);
}
__device__ __forceinline__ unsigned short f2bf(float f) {
    unsigned int u = __float_as_uint(f);
    unsigned int r = u + 0x7FFFu + ((u >> 16) & 1u);  // RNE
    return (unsigned short)(r >> 16);
}
__device__ __forceinline__ unsigned int pack2bf(float a, float b) {
    return (unsigned int)f2bf(a) | ((unsigned int)f2bf(b) << 16);
}

#if !FP8_HW
__device__ __forceinline__ unsigned int f2fp8_sw(float v) {
    unsigned int u = __float_as_uint(v);
    unsigned int s = (u >> 24) & 0x80u;
    unsigned int a = u & 0x7FFFFFFFu;
    float av = __uint_as_float(a);
    unsigned int q;
    if (av >= 0.015625f) {
        unsigned int r = a + 0x7FFFFu + ((a >> 20) & 1u);
        q = (r - (120u << 23)) >> 20;
        if (q > 0x7Eu) q = 0x7Eu;
    } else {
        q = (unsigned int)(av * 512.0f + 0.5f);
    }
    return s | q;
}
__device__ __forceinline__ float fp8_dec_sw(unsigned int u8) {
    unsigned int s = (u8 & 0x80u) << 24;
    unsigned int em = u8 & 0x7Fu;
    float vn = __uint_as_float(s | ((em << 20) + (120u << 23)));
    float vs = __uint_as_float(s | 0x3B000000u) * (float)(int)em;
    return em >= 8 ? vn : vs;
}
#endif

__device__ __forceinline__ void fp8x4_dec(unsigned int d, float& x, float& y, float& z, float& w) {
#if FP8_HW
    f32x2 lo = __builtin_amdgcn_cvt_pk_f32_fp8((int)d, false);
    f32x2 hi = __builtin_amdgcn_cvt_pk_f32_fp8((int)d, true);
    x = lo.x; y = lo.y; z = hi.x; w = hi.y;
#else
    x = fp8_dec_sw(d & 0xFFu);
    y = fp8_dec_sw((d >> 8) & 0xFFu);
    z = fp8_dec_sw((d >> 16) & 0xFFu);
    w = fp8_dec_sw((d >> 24) & 0xFFu);
#endif
}
__device__ __forceinline__ unsigned int fp8x4_enc(float a, float b, float c, float d) {
#if FP8_HW
    int u = __builtin_amdgcn_cvt_pk_fp8_f32(a, b, 0, false);
    u = __builtin_amdgcn_cvt_pk_fp8_f32(c, d, u, true);
    return (unsigned int)u;
#else
    return f2fp8_sw(a) | (f2fp8_sw(b) << 8) | (f2fp8_sw(c) << 16) | (f2fp8_sw(d) << 24);
#endif
}

// ---------- megaA: partition + feat conv (bf16 + fp8) + weight conv ----------
__global__ __launch_bounds__(256) void megaA(const int* __restrict__ esrc, const int* __restrict__ edst,
                                             int* __restrict__ gcur, unsigned int* __restrict__ pairs,
                                             int E, int NB,
                                             const float* __restrict__ feat, unsigned short* __restrict__ Fb,
                                             unsigned char* __restrict__ Ff8, int nquad,
                                             const float* __restrict__ W0, unsigned short* __restrict__ Wb1,
                                             const float* __restrict__ W1, unsigned short* __restrict__ Wb2,
                                             int pblocks, int cblocks) {
    __shared__ int bcnt[256];
    __shared__ int bbas[256];
    int b = blockIdx.x, t = threadIdx.x;
    if (b < pblocks) {
        int e0 = b * 4096;
        int eend = min(e0 + 4096, E);
        if (t < NB) bcnt[t] = 0;
        __syncthreads();
        for (int e = e0 + t; e < eend; e += 256) atomicAdd(&bcnt[edst[e] >> BSH], 1);
        __syncthreads();
        if (t < NB) {
            bbas[t] = t * BCAP + atomicAdd(&gcur[t], bcnt[t]);
            bcnt[t] = 0;
        }
        __syncthreads();
        for (int e = e0 + t; e < eend; e += 256) {
            int d = edst[e];
            int s = esrc[e];
            int bk = d >> BSH;
            int off = atomicAdd(&bcnt[bk], 1);
            pairs[bbas[bk] + off] = (unsigned int)s | ((unsigned int)(d & ((1 << BSH) - 1)) << 17);
        }
    } else if (b < pblocks + cblocks) {
        int cb = b - pblocks;
        for (int q = cb * 256 + t; q < nquad; q += cblocks * 256) {
            float4 f = *(const float4*)(feat + (size_t)q * 4);
            ushort4 ub;
            ub.x = f2bf(f.x); ub.y = f2bf(f.y); ub.z = f2bf(f.z); ub.w = f2bf(f.w);
            *(ushort4*)(Fb + (size_t)q * 4) = ub;
            *(unsigned int*)(Ff8 + (size_t)q * 4) = fp8x4_enc(f.x, f.y, f.z, f.w);
        }
    } else {
        int wb = b - pblocks - cblocks;
        for (int i = wb * 256 + t; i < 49152; i += 24 * 256) {
            if (i < 32768) {
                Wb1[i] = f2bf(W0[i]);
            } else {
                int i2 = i - 32768;
                int j = i2 >> 7, k = i2 & 127;
                float vv = (j < 64) ? W1[j * 256 + k] : W1[(j - 64) * 256 + 128 + k];
                Wb2[i2] = f2bf(vv);
            }
        }
    }
}

// ---------- build: in-block bucket scan + per-node offsets + csr placement ----------
__global__ __launch_bounds__(256) void build(const unsigned int* __restrict__ pairs,
                                             const int* __restrict__ gcur,
                                             int* __restrict__ offs, int* __restrict__ csr,
                                             int n, int NB, int E) {
    __shared__ int cnt[512];
    __shared__ int excl[512];
    __shared__ int wsum[4];
    __shared__ int woff[4];
    __shared__ int sbase;
    int b = blockIdx.x, t = threadIdx.x, lane = t & 63, wv = t >> 6;

    {
        int vv = (t < NB) ? gcur[t] : 0;
        int x = vv;
#pragma unroll
        for (int o = 1; o < 64; o <<= 1) {
            int y = __shfl_up(x, o, 64);
            if (lane >= o) x += y;
        }
        if (lane == 63) wsum[wv] = x;
        __syncthreads();
        if (t == 0) {
            int r = 0;
            for (int w = 0; w < 4; ++w) { woff[w] = r; r += wsum[w]; }
        }
        __syncthreads();
        if (t == b) sbase = woff[wv] + x - vv;
        if (b == 0 && t == 0) offs[n] = E;
    }
    __syncthreads();
    int base = sbase;
    int p0 = b * BCAP;
    int m = gcur[b];
    int v0 = b << BSH;

    cnt[t] = 0;
    cnt[t + 256] = 0;
    __syncthreads();
    for (int i = t; i < m; i += 256) atomicAdd(&cnt[pairs[p0 + i] >> 17], 1);
    __syncthreads();
    int c0 = cnt[2 * t], c1 = cnt[2 * t + 1];
    int s = c0 + c1;
    int x = s;
#pragma unroll
    for (int o = 1; o < 64; o <<= 1) {
        int y = __shfl_up(x, o, 64);
        if (lane >= o) x += y;
    }
    if (lane == 63) wsum[wv] = x;
    __syncthreads();
    if (t == 0) {
        int r = 0;
        for (int w = 0; w < 4; ++w) { woff[w] = r; r += wsum[w]; }
    }
    __syncthreads();
    int ex = woff[wv] + x - s;
    excl[2 * t] = ex;
    excl[2 * t + 1] = ex + c0;
    int v = v0 + 2 * t;
    if (v + 1 < n) {
        int2 o2;
        o2.x = base + ex;
        o2.y = base + ex + c0;
        *(int2*)(offs + v) = o2;
    } else if (v < n) {
        offs[v] = base + ex;
    }
    cnt[t] = 0;
    cnt[t + 256] = 0;
    __syncthreads();
    for (int i = t; i < m; i += 256) {
        unsigned int u = pairs[p0 + i];
        int dl = u >> 17;
        int off = atomicAdd(&cnt[dl], 1);
        csr[base + excl[dl] + off] = (int)(u & 0x1FFFFu);
    }
}

// ---------- agg1: Mb[v] = mean_{u in N(v)} fp8(feat[u]) -> bf16 [n][128] ----------
// quarter-wave (16 lanes) per node: uint2 = 8B/lane, 16 lanes = full 128B row.
// 16 edges in flight with split accumulator sets to break FP-add dep chains.
__global__ __launch_bounds__(256) void agg1(const unsigned char* __restrict__ Ff8,
                                            const int* __restrict__ offs,
                                            const int* __restrict__ csr,
                                            unsigned short* __restrict__ Mb, int n) {
    int t = threadIdx.x;
    int q = t >> 4, cl = t & 15;
    int v = blockIdx.x * 16 + q;
    if (v >= n) return;
    int beg = offs[v], end = offs[v + 1];
    float a0 = 0.f, a1 = 0.f, a2 = 0.f, a3 = 0.f;
    float a4 = 0.f, a5 = 0.f, a6 = 0.f, a7 = 0.f;
    float b0 = 0.f, b1 = 0.f, b2 = 0.f, b3 = 0.f;
    float b4 = 0.f, b5 = 0.f, b6 = 0.f, b7 = 0.f;
    int e = beg;
    for (; e + 15 < end; e += 16) {
        int s[16];
#pragma unroll
        for (int k = 0; k < 16; ++k) s[k] = csr[e + k];
        uint2 d[16];
#pragma unroll
        for (int k = 0; k < 16; ++k)
            d[k] = *(const uint2*)(Ff8 + (size_t)s[k] * 128 + cl * 8);
#pragma unroll
        for (int k = 0; k < 16; k += 2) {
            float x0, y0, z0, w0, x1, y1, z1, w1;
            fp8x4_dec(d[k].x, x0, y0, z0, w0);
            fp8x4_dec(d[k].y, x1, y1, z1, w1);
            a0 += x0; a1 += y0; a2 += z0; a3 += w0;
            a4 += x1; a5 += y1; a6 += z1; a7 += w1;
            fp8x4_dec(d[k + 1].x, x0, y0, z0, w0);
            fp8x4_dec(d[k + 1].y, x1, y1, z1, w1);
            b0 += x0; b1 += y0; b2 += z0; b3 += w0;
            b4 += x1; b5 += y1; b6 += z1; b7 += w1;
        }
    }
    for (; e + 7 < end; e += 8) {
        int s[8];
#pragma unroll
        for (int k = 0; k < 8; ++k) s[k] = csr[e + k];
        uint2 d[8];
#pragma unroll
        for (int k = 0; k < 8; ++k)
            d[k] = *(const uint2*)(Ff8 + (size_t)s[k] * 128 + cl * 8);
#pragma unroll
        for (int k = 0; k < 8; ++k) {
            float x0, y0, z0, w0, x1, y1, z1, w1;
            fp8x4_dec(d[k].x, x0, y0, z0, w0);
            fp8x4_dec(d[k].y, x1, y1, z1, w1);
            a0 += x0; a1 += y0; a2 += z0; a3 += w0;
            a4 += x1; a5 += y1; a6 += z1; a7 += w1;
        }
    }
    for (; e < end; ++e) {
        uint2 d0 = *(const uint2*)(Ff8 + (size_t)csr[e] * 128 + cl * 8);
        float x0, y0, z0, w0, x1, y1, z1, w1;
        fp8x4_dec(d0.x, x0, y0, z0, w0);
        fp8x4_dec(d0.y, x1, y1, z1, w1);
        a0 += x0; a1 += y0; a2 += z0; a3 += w0;
        a4 += x1; a5 += y1; a6 += z1; a7 += w1;
    }
    a0 += b0; a1 += b1; a2 += b2; a3 += b3;
    a4 += b4; a5 += b5; a6 += b6; a7 += b7;
    int deg = end - beg;
    float inv = 1.0f / (float)(deg > 0 ? deg : 1);
    uint4 pk;
    pk.x = pack2bf(a0 * inv, a1 * inv);
    pk.y = pack2bf(a2 * inv, a3 * inv);
    pk.z = pack2bf(a4 * inv, a5 * inv);
    pk.w = pack2bf(a6 * inv, a7 * inv);
    *(uint4*)(Mb + (size_t)v * 128 + cl * 8) = pk;
}

// ---------- fused GEMM, W-stationary: wave w owns outs [w*32,w*32+32), all 64 nodes ----------
// 2 contiguous tiles per block (weight fragments amortized); 4-bit hT swizzle; 16 KB LDS overlay.
__global__ __launch_bounds__(256) void fused_gemm(const unsigned short* __restrict__ Fb,  // [n][128]
                                                  const unsigned short* __restrict__ Mb,  // [n][128]
                                                  const unsigned short* __restrict__ Wb1, // [128][256]
                                                  const unsigned short* __restrict__ Wc,  // [128][128]
                                                  unsigned short* __restrict__ Za,        // [n][64] bf16
                                                  unsigned char* __restrict__ Zb8,        // [n][64] fp8
                                                  int n, int ntiles) {
    __shared__ __align__(16) unsigned char smem[16384];  // hT [64][256B swz]; later zaT/zbT overlay
    int t = threadIdx.x, l = t & 63, w = t >> 6;
    int lr = l & 15;
    int lk8 = (l >> 4) * 8;
    int rbase = (l >> 4) * 4;

    // ---- load this wave's weight fragments ONCE (96 VGPR) ----
    bf16x8 w1f[2][8];
#pragma unroll
    for (int of = 0; of < 2; ++of)
#pragma unroll
        for (int kc = 0; kc < 8; ++kc)
            w1f[of][kc] = *(const bf16x8*)(Wb1 + (size_t)(w * 32 + of * 16 + lr) * 256 + kc * 32 + lk8);
    bf16x8 w2f[2][4];
#pragma unroll
    for (int of = 0; of < 2; ++of)
#pragma unroll
        for (int kc = 0; kc < 4; ++kc)
            w2f[of][kc] = *(const bf16x8*)(Wc + (size_t)(w * 32 + of * 16 + lr) * 128 + kc * 32 + lk8);

#pragma unroll 1
    for (int it = 0; it < 2; ++it) {
        int tile = blockIdx.x * 2 + it;
        if (tile >= ntiles) break;
        int m0 = tile * 64;

        // ---- phase 1: h^T = relu(Wb1 · cat^T); wave covers 4 node-frags ----
        f32x4 acc[2][4];
#pragma unroll
        for (int of = 0; of < 2; ++of)
#pragma unroll
            for (int nf = 0; nf < 4; ++nf) acc[of][nf] = (f32x4){0.f, 0.f, 0.f, 0.f};
#pragma unroll
        for (int nf = 0; nf < 4; ++nf) {
            int node = m0 + nf * 16 + lr;
            node = (node < n) ? node : (n - 1);
#pragma unroll
            for (int kc = 0; kc < 8; ++kc) {
                int kb = kc * 32 + lk8;
                bf16x8 x;
                if (kb < 128)
                    x = *(const bf16x8*)(Fb + (size_t)node * 128 + kb);
                else
                    x = *(const bf16x8*)(Mb + (size_t)node * 128 + (kb - 128));
                acc[0][nf] = __builtin_amdgcn_mfma_f32_16x16x32_bf16(w1f[0][kc], x, acc[0][nf], 0, 0, 0);
                acc[1][nf] = __builtin_amdgcn_mfma_f32_16x16x32_bf16(w1f[1][kc], x, acc[1][nf], 0, 0, 0);
            }
        }
        // stage h: lane holds outs (w*32+of*16+rbase..+3) for node (nf*16+lr) -> b64 4-bit-swz writes
#pragma unroll
        for (int of = 0; of < 2; ++of)
#pragma unroll
            for (int nf = 0; nf < 4; ++nf) {
                int node = nf * 16 + lr;
                unsigned int ob = (unsigned int)((w * 32 + of * 16 + rbase) * 2);
                uint2 pk;
                pk.x = pack2bf(fmaxf(acc[of][nf][0], 0.f), fmaxf(acc[of][nf][1], 0.f));
                pk.y = pack2bf(fmaxf(acc[of][nf][2], 0.f), fmaxf(acc[of][nf][3], 0.f));
                *(uint2*)(smem + node * 256 + (ob ^ ((unsigned int)(node & 15) << 4))) = pk;
            }
        __syncthreads();  // hT complete

        // ---- phase 2: Z^T = Wc · h^T ----
        f32x4 acc2[2][4];
#pragma unroll
        for (int of = 0; of < 2; ++of)
#pragma unroll
            for (int nf = 0; nf < 4; ++nf) acc2[of][nf] = (f32x4){0.f, 0.f, 0.f, 0.f};
#pragma unroll
        for (int nf = 0; nf < 4; ++nf) {
            int node = nf * 16 + lr;
            unsigned int sw2 = (unsigned int)(node & 15) << 4;
#pragma unroll
            for (int kc = 0; kc < 4; ++kc) {
                unsigned int kbyte = (unsigned int)((kc * 32 + lk8) * 2);
                bf16x8 x = *(const bf16x8*)(smem + node * 256 + (kbyte ^ sw2));
                acc2[0][nf] = __builtin_amdgcn_mfma_f32_16x16x32_bf16(w2f[0][kc], x, acc2[0][nf], 0, 0, 0);
                acc2[1][nf] = __builtin_amdgcn_mfma_f32_16x16x32_bf16(w2f[1][kc], x, acc2[1][nf], 0, 0, 0);
            }
        }
        __syncthreads();  // all waves done reading hT; overlay zaT/zbT

        // stage Z: waves 0,1 -> Za (outs 0..63 bf16, [64][128B]); waves 2,3 -> Zb (outs 64..127 fp8)
        {
            unsigned char* zaT = smem;         // 8 KB
            unsigned char* zbT = smem + 8192;  // 4 KB
#pragma unroll
            for (int of = 0; of < 2; ++of)
#pragma unroll
                for (int nf = 0; nf < 4; ++nf) {
                    int node = nf * 16 + lr;
                    int out = w * 32 + of * 16 + rbase;
                    if (w < 2) {
                        uint2 pk;
                        pk.x = pack2bf(acc2[of][nf][0], acc2[of][nf][1]);
                        pk.y = pack2bf(acc2[of][nf][2], acc2[of][nf][3]);
                        unsigned int ob = (unsigned int)(out * 2);
                        *(uint2*)(zaT + node * 128 + (ob ^ ((unsigned int)(node & 7) << 4))) = pk;
                    } else {
                        unsigned int pk = fp8x4_enc(acc2[of][nf][0], acc2[of][nf][1],
                                                    acc2[of][nf][2], acc2[of][nf][3]);
                        unsigned int ob = (unsigned int)(out - 64);
                        *(unsigned int*)(zbT + node * 64 + (ob ^ ((unsigned int)(node & 3) << 4))) = pk;
                    }
                }
        }
        __syncthreads();

        // coalesced global stores (un-swizzling 16B chunks)
#pragma unroll
        for (int c = 0; c < 2; ++c) {  // Za: 512 x 16B
            int chunk = c * 256 + t;
            int row = chunk >> 3, cb = (chunk & 7) * 16;
            int grow = m0 + row;
            if (grow < n)
                *(uint4*)((unsigned char*)Za + (size_t)grow * 128 + cb) =
                    *(const uint4*)(smem + row * 128 + (cb ^ ((row & 7) << 4)));
        }
        {  // Zb: 256 x 16B
            int row = t >> 2, cb = (t & 3) * 16;
            int grow = m0 + row;
            if (grow < n)
                *(uint4*)(Zb8 + (size_t)grow * 64 + cb) =
                    *(const uint4*)(smem + 8192 + row * 64 + (cb ^ ((row & 3) << 4)));
        }
        __syncthreads();  // LDS reads of this tile's stores done before next tile's hT writes
    }
}

// ---------- agg2: out[v] = f32(Za[v]) + mean_u fp8(Zb[u]); quarter-wave per node ----------
__global__ __launch_bounds__(256) void agg2(const unsigned short* __restrict__ Za,
                                            const unsigned char* __restrict__ Zb8,
                                            const int* __restrict__ offs,
                                            const int* __restrict__ csr,
                                            float* __restrict__ out, int n) {
    int t = threadIdx.x;
    int q = t >> 4, cl = t & 15;
    int v = blockIdx.x * 16 + q;
    if (v >= n) return;
    int beg = offs[v], end = offs[v + 1];
    float a0 = 0.f, a1 = 0.f, a2 = 0.f, a3 = 0.f;
    float b0 = 0.f, b1 = 0.f, b2 = 0.f, b3 = 0.f;
    int e = beg;
    for (; e + 15 < end; e += 16) {
        int s[16];
#pragma unroll
        for (int k = 0; k < 16; ++k) s[k] = csr[e + k];
        unsigned int d[16];
#pragma unroll
        for (int k = 0; k < 16; ++k)
            d[k] = *(const unsigned int*)(Zb8 + (size_t)s[k] * 64 + cl * 4);
#pragma unroll
        for (int k = 0; k < 16; k += 2) {
            float x, y, z, u2;
            fp8x4_dec(d[k], x, y, z, u2);
            a0 += x; a1 += y; a2 += z; a3 += u2;
            fp8x4_dec(d[k + 1], x, y, z, u2);
            b0 += x; b1 += y; b2 += z; b3 += u2;
        }
    }
    for (; e + 7 < end; e += 8) {
        int s[8];
#pragma unroll
        for (int k = 0; k < 8; ++k) s[k] = csr[e + k];
        unsigned int d[8];
#pragma unroll
        for (int k = 0; k < 8; ++k)
            d[k] = *(const unsigned int*)(Zb8 + (size_t)s[k] * 64 + cl * 4);
#pragma unroll
        for (int k = 0; k < 8; ++k) {
            float x, y, z, u2;
            fp8x4_dec(d[k], x, y, z, u2);
            a0 += x; a1 += y; a2 += z; a3 += u2;
        }
    }
    for (; e < end; ++e) {
        unsigned int d0 = *(const unsigned int*)(Zb8 + (size_t)csr[e] * 64 + cl * 4);
        float x, y, z, u2;
        fp8x4_dec(d0, x, y, z, u2);
        a0 += x; a1 += y; a2 += z; a3 += u2;
    }
    a0 += b0; a1 += b1; a2 += b2; a3 += b3;
    int deg = end - beg;
    float inv = 1.0f / (float)(deg > 0 ? deg : 1);
    uint2 uz = *(const uint2*)((const unsigned char*)Za + (size_t)v * 128 + cl * 8);
    float4 o;
    o.x = bf2f((unsigned short)uz.x) + a0 * inv;
    o.y = bf2f((unsigned short)(uz.x >> 16)) + a1 * inv;
    o.z = bf2f((unsigned short)uz.y) + a2 * inv;
    o.w = bf2f((unsigned short)(uz.y >> 16)) + a3 * inv;
    *(float4*)(out + (size_t)v * 64 + cl * 4) = o;
}

extern "C" void kernel_launch(void* const* d_in, const int* in_sizes, int n_in,
                              void* d_out, int out_size, void* d_ws, size_t ws_size,
                              hipStream_t stream) {
    const float* feat = (const float*)d_in[0];
    const int* esrc = (const int*)d_in[1];
    const int* edst = (const int*)d_in[2];
    const float* W0 = (const float*)d_in[3];  // [128, 256]
    const float* W1 = (const float*)d_in[4];  // [64, 256]
    float* out = (float*)d_out;

    int n = in_sizes[0] / 128;  // 100000
    int E = in_sizes[1];        // 1600000
    int NB = (n + 511) >> 9;    // 196 buckets

    char* ws = (char*)d_ws;
    size_t off = 0;
    auto alloc = [&](size_t bytes) -> void* {
        void* p = ws + off;
        off += (bytes + 255) & ~(size_t)255;
        return p;
    };
    int* offs = (int*)alloc((size_t)(n + 1) * 4);
    int* csr = (int*)alloc((size_t)E * 4);
    int* gcur = (int*)alloc((size_t)NB * 4);
    unsigned int* pairs = (unsigned int*)alloc((size_t)NB * BCAP * 4);
    unsigned short* Wb1 = (unsigned short*)alloc((size_t)128 * 256 * 2);
    unsigned short* Wb2 = (unsigned short*)alloc((size_t)128 * 128 * 2);
    unsigned short* Fb = (unsigned short*)alloc((size_t)n * 128 * 2);
    unsigned char* Ff8 = (unsigned char*)alloc((size_t)n * 128);
    unsigned short* Mb = (unsigned short*)alloc((size_t)n * 128 * 2);
    unsigned short* Za = (unsigned short*)alloc((size_t)n * 64 * 2);
    unsigned char* Zb8 = (unsigned char*)alloc((size_t)n * 64);

    int pblocks = (E + 4095) / 4096;  // 391
    int cblocks = 640;
    int nquad = n * 32;

    hipMemsetAsync(gcur, 0, (size_t)NB * 4, stream);
    megaA<<<pblocks + cblocks + 24, 256, 0, stream>>>(esrc, edst, gcur, pairs, E, NB,
                                                      feat, Fb, Ff8, nquad,
                                                      W0, Wb1, W1, Wb2, pblocks, cblocks);
    build<<<NB, 256, 0, stream>>>(pairs, gcur, offs, csr, n, NB, E);

    agg1<<<(n + 15) / 16, 256, 0, stream>>>(Ff8, offs, csr, Mb, n);
    int ntiles = (n + 63) / 64;  // 1563
    fused_gemm<<<(ntiles + 1) / 2, 256, 0, stream>>>(Fb, Mb, Wb1, Wb2, Za, Zb8, n, ntiles);
    agg2<<<(n + 15) / 16, 256, 0, stream>>>(Za, Zb8, offs, csr, out, n);
}

// Round 12
// 181.041 us; speedup vs baseline: 1.0542x; 1.0542x over previous
//
#include <hip/hip_runtime.h>
#include <hip/hip_bf16.h>

typedef __attribute__((ext_vector_type(8))) short bf16x8;
typedef __attribute__((ext_vector_type(4))) float f32x4;
typedef __attribute__((ext_vector_type(2))) float f32x2;

#define BSH 9       // nodes per bucket = 512
#define BCAP 12288  // per-bucket pair capacity (mean 8163, std ~90)

#if __has_builtin(__builtin_amdgcn_cvt_pk_f32_fp8) && __has_builtin(__builtin_amdgcn_cvt_pk_fp8_f32)
#define FP8_HW 1
#else
#define FP8_HW 0
#endif

// ---------- helpers ----------
__device__ __forceinline__ float bf2f(unsigned short u) {
    return __uint_as_float(((unsigned int)u) << 16);
}
__device__ __forceinline__ unsigned short f2bf(float f) {
    unsigned int u = __float_as_uint(f);
    unsigned int r = u + 0x7FFFu + ((u >> 16) & 1u);  // RNE
    return (unsigned short)(r >> 16);
}
__device__ __forceinline__ unsigned int pack2bf(float a, float b) {
    return (unsigned int)f2bf(a) | ((unsigned int)f2bf(b) << 16);
}

#if !FP8_HW
__device__ __forceinline__ unsigned int f2fp8_sw(float v) {
    unsigned int u = __float_as_uint(v);
    unsigned int s = (u >> 24) & 0x80u;
    unsigned int a = u & 0x7FFFFFFFu;
    float av = __uint_as_float(a);
    unsigned int q;
    if (av >= 0.015625f) {
        unsigned int r = a + 0x7FFFFu + ((a >> 20) & 1u);
        q = (r - (120u << 23)) >> 20;
        if (q > 0x7Eu) q = 0x7Eu;
    } else {
        q = (unsigned int)(av * 512.0f + 0.5f);
    }
    return s | q;
}
__device__ __forceinline__ float fp8_dec_sw(unsigned int u8) {
    unsigned int s = (u8 & 0x80u) << 24;
    unsigned int em = u8 & 0x7Fu;
    float vn = __uint_as_float(s | ((em << 20) + (120u << 23)));
    float vs = __uint_as_float(s | 0x3B000000u) * (float)(int)em;
    return em >= 8 ? vn : vs;
}
#endif

__device__ __forceinline__ void fp8x4_dec(unsigned int d, float& x, float& y, float& z, float& w) {
#if FP8_HW
    f32x2 lo = __builtin_amdgcn_cvt_pk_f32_fp8((int)d, false);
    f32x2 hi = __builtin_amdgcn_cvt_pk_f32_fp8((int)d, true);
    x = lo.x; y = lo.y; z = hi.x; w = hi.y;
#else
    x = fp8_dec_sw(d & 0xFFu);
    y = fp8_dec_sw((d >> 8) & 0xFFu);
    z = fp8_dec_sw((d >> 16) & 0xFFu);
    w = fp8_dec_sw((d >> 24) & 0xFFu);
#endif
}
__device__ __forceinline__ unsigned int fp8x4_enc(float a, float b, float c, float d) {
#if FP8_HW
    int u = __builtin_amdgcn_cvt_pk_fp8_f32(a, b, 0, false);
    u = __builtin_amdgcn_cvt_pk_fp8_f32(c, d, u, true);
    return (unsigned int)u;
#else
    return f2fp8_sw(a) | (f2fp8_sw(b) << 8) | (f2fp8_sw(c) << 16) | (f2fp8_sw(d) << 24);
#endif
}

// ---------- megaA: partition + feat conv (bf16 + fp8) + weight conv ----------
__global__ __launch_bounds__(256) void megaA(const int* __restrict__ esrc, const int* __restrict__ edst,
                                             int* __restrict__ gcur, unsigned int* __restrict__ pairs,
                                             int E, int NB,
                                             const float* __restrict__ feat, unsigned short* __restrict__ Fb,
                                             unsigned char* __restrict__ Ff8, int nquad,
                                             const float* __restrict__ W0, unsigned short* __restrict__ Wb1,
                                             const float* __restrict__ W1, unsigned short* __restrict__ Wb2,
                                             int pblocks, int cblocks) {
    __shared__ int bcnt[256];
    __shared__ int bbas[256];
    int b = blockIdx.x, t = threadIdx.x;
    if (b < pblocks) {
        int e0 = b * 4096;
        int eend = min(e0 + 4096, E);
        if (t < NB) bcnt[t] = 0;
        __syncthreads();
        for (int e = e0 + t; e < eend; e += 256) atomicAdd(&bcnt[edst[e] >> BSH], 1);
        __syncthreads();
        if (t < NB) {
            bbas[t] = t * BCAP + atomicAdd(&gcur[t], bcnt[t]);
            bcnt[t] = 0;
        }
        __syncthreads();
        for (int e = e0 + t; e < eend; e += 256) {
            int d = edst[e];
            int s = esrc[e];
            int bk = d >> BSH;
            int off = atomicAdd(&bcnt[bk], 1);
            pairs[bbas[bk] + off] = (unsigned int)s | ((unsigned int)(d & ((1 << BSH) - 1)) << 17);
        }
    } else if (b < pblocks + cblocks) {
        int cb = b - pblocks;
        for (int q = cb * 256 + t; q < nquad; q += cblocks * 256) {
            float4 f = *(const float4*)(feat + (size_t)q * 4);
            ushort4 ub;
            ub.x = f2bf(f.x); ub.y = f2bf(f.y); ub.z = f2bf(f.z); ub.w = f2bf(f.w);
            *(ushort4*)(Fb + (size_t)q * 4) = ub;
            *(unsigned int*)(Ff8 + (size_t)q * 4) = fp8x4_enc(f.x, f.y, f.z, f.w);
        }
    } else {
        int wb = b - pblocks - cblocks;
        for (int i = wb * 256 + t; i < 49152; i += 24 * 256) {
            if (i < 32768) {
                Wb1[i] = f2bf(W0[i]);
            } else {
                int i2 = i - 32768;
                int j = i2 >> 7, k = i2 & 127;
                float vv = (j < 64) ? W1[j * 256 + k] : W1[(j - 64) * 256 + 128 + k];
                Wb2[i2] = f2bf(vv);
            }
        }
    }
}

// ---------- build: in-block bucket scan + per-node offsets + csr placement ----------
__global__ __launch_bounds__(256) void build(const unsigned int* __restrict__ pairs,
                                             const int* __restrict__ gcur,
                                             int* __restrict__ offs, int* __restrict__ csr,
                                             int n, int NB, int E) {
    __shared__ int cnt[512];
    __shared__ int excl[512];
    __shared__ int wsum[4];
    __shared__ int woff[4];
    __shared__ int sbase;
    int b = blockIdx.x, t = threadIdx.x, lane = t & 63, wv = t >> 6;

    {
        int vv = (t < NB) ? gcur[t] : 0;
        int x = vv;
#pragma unroll
        for (int o = 1; o < 64; o <<= 1) {
            int y = __shfl_up(x, o, 64);
            if (lane >= o) x += y;
        }
        if (lane == 63) wsum[wv] = x;
        __syncthreads();
        if (t == 0) {
            int r = 0;
            for (int w = 0; w < 4; ++w) { woff[w] = r; r += wsum[w]; }
        }
        __syncthreads();
        if (t == b) sbase = woff[wv] + x - vv;
        if (b == 0 && t == 0) offs[n] = E;
    }
    __syncthreads();
    int base = sbase;
    int p0 = b * BCAP;
    int m = gcur[b];
    int v0 = b << BSH;

    cnt[t] = 0;
    cnt[t + 256] = 0;
    __syncthreads();
    for (int i = t; i < m; i += 256) atomicAdd(&cnt[pairs[p0 + i] >> 17], 1);
    __syncthreads();
    int c0 = cnt[2 * t], c1 = cnt[2 * t + 1];
    int s = c0 + c1;
    int x = s;
#pragma unroll
    for (int o = 1; o < 64; o <<= 1) {
        int y = __shfl_up(x, o, 64);
        if (lane >= o) x += y;
    }
    if (lane == 63) wsum[wv] = x;
    __syncthreads();
    if (t == 0) {
        int r = 0;
        for (int w = 0; w < 4; ++w) { woff[w] = r; r += wsum[w]; }
    }
    __syncthreads();
    int ex = woff[wv] + x - s;
    excl[2 * t] = ex;
    excl[2 * t + 1] = ex + c0;
    int v = v0 + 2 * t;
    if (v + 1 < n) {
        int2 o2;
        o2.x = base + ex;
        o2.y = base + ex + c0;
        *(int2*)(offs + v) = o2;
    } else if (v < n) {
        offs[v] = base + ex;
    }
    cnt[t] = 0;
    cnt[t + 256] = 0;
    __syncthreads();
    for (int i = t; i < m; i += 256) {
        unsigned int u = pairs[p0 + i];
        int dl = u >> 17;
        int off = atomicAdd(&cnt[dl], 1);
        csr[base + excl[dl] + off] = (int)(u & 0x1FFFFu);
    }
}

// ---------- agg1: Mb[v] = mean_{u in N(v)} fp8(feat[u]) -> bf16 [n][128] ----------
// quarter-wave (16 lanes) per node: uint2 load = 8B/lane, 16 lanes = full 128B row.
// 8 edges in flight; low VGPR (32) for max occupancy (TLP > ILP here — R11 lesson).
__global__ __launch_bounds__(256) void agg1(const unsigned char* __restrict__ Ff8,
                                            const int* __restrict__ offs,
                                            const int* __restrict__ csr,
                                            unsigned short* __restrict__ Mb, int n) {
    int t = threadIdx.x;
    int q = t >> 4, cl = t & 15;
    int v = blockIdx.x * 16 + q;
    if (v >= n) return;
    int beg = offs[v], end = offs[v + 1];
    float a0 = 0.f, a1 = 0.f, a2 = 0.f, a3 = 0.f;
    float a4 = 0.f, a5 = 0.f, a6 = 0.f, a7 = 0.f;
    int e = beg;
    for (; e + 7 < end; e += 8) {
        int s[8];
#pragma unroll
        for (int k = 0; k < 8; ++k) s[k] = csr[e + k];
        uint2 d[8];
#pragma unroll
        for (int k = 0; k < 8; ++k)
            d[k] = *(const uint2*)(Ff8 + (size_t)s[k] * 128 + cl * 8);
#pragma unroll
        for (int k = 0; k < 8; ++k) {
            float x0, y0, z0, w0, x1, y1, z1, w1;
            fp8x4_dec(d[k].x, x0, y0, z0, w0);
            fp8x4_dec(d[k].y, x1, y1, z1, w1);
            a0 += x0; a1 += y0; a2 += z0; a3 += w0;
            a4 += x1; a5 += y1; a6 += z1; a7 += w1;
        }
    }
    for (; e < end; ++e) {
        uint2 d0 = *(const uint2*)(Ff8 + (size_t)csr[e] * 128 + cl * 8);
        float x0, y0, z0, w0, x1, y1, z1, w1;
        fp8x4_dec(d0.x, x0, y0, z0, w0);
        fp8x4_dec(d0.y, x1, y1, z1, w1);
        a0 += x0; a1 += y0; a2 += z0; a3 += w0;
        a4 += x1; a5 += y1; a6 += z1; a7 += w1;
    }
    int deg = end - beg;
    float inv = 1.0f / (float)(deg > 0 ? deg : 1);
    uint4 pk;
    pk.x = pack2bf(a0 * inv, a1 * inv);
    pk.y = pack2bf(a2 * inv, a3 * inv);
    pk.z = pack2bf(a4 * inv, a5 * inv);
    pk.w = pack2bf(a6 * inv, a7 * inv);
    *(uint4*)(Mb + (size_t)v * 128 + cl * 8) = pk;
}

// ---------- fused GEMM, W-stationary: wave w owns outs [w*32,w*32+32), all 64 nodes ----------
// 2 contiguous tiles per block (weight fragments amortized); 4-bit hT swizzle; 16 KB LDS overlay.
__global__ __launch_bounds__(256) void fused_gemm(const unsigned short* __restrict__ Fb,  // [n][128]
                                                  const unsigned short* __restrict__ Mb,  // [n][128]
                                                  const unsigned short* __restrict__ Wb1, // [128][256]
                                                  const unsigned short* __restrict__ Wc,  // [128][128]
                                                  unsigned short* __restrict__ Za,        // [n][64] bf16
                                                  unsigned char* __restrict__ Zb8,        // [n][64] fp8
                                                  int n, int ntiles) {
    __shared__ __align__(16) unsigned char smem[16384];  // hT [64][256B swz]; later zaT/zbT overlay
    int t = threadIdx.x, l = t & 63, w = t >> 6;
    int lr = l & 15;
    int lk8 = (l >> 4) * 8;
    int rbase = (l >> 4) * 4;

    // ---- load this wave's weight fragments ONCE (96 VGPR) ----
    bf16x8 w1f[2][8];
#pragma unroll
    for (int of = 0; of < 2; ++of)
#pragma unroll
        for (int kc = 0; kc < 8; ++kc)
            w1f[of][kc] = *(const bf16x8*)(Wb1 + (size_t)(w * 32 + of * 16 + lr) * 256 + kc * 32 + lk8);
    bf16x8 w2f[2][4];
#pragma unroll
    for (int of = 0; of < 2; ++of)
#pragma unroll
        for (int kc = 0; kc < 4; ++kc)
            w2f[of][kc] = *(const bf16x8*)(Wc + (size_t)(w * 32 + of * 16 + lr) * 128 + kc * 32 + lk8);

#pragma unroll 1
    for (int it = 0; it < 2; ++it) {
        int tile = blockIdx.x * 2 + it;
        if (tile >= ntiles) break;
        int m0 = tile * 64;

        // ---- phase 1: h^T = relu(Wb1 · cat^T); wave covers 4 node-frags ----
        f32x4 acc[2][4];
#pragma unroll
        for (int of = 0; of < 2; ++of)
#pragma unroll
            for (int nf = 0; nf < 4; ++nf) acc[of][nf] = (f32x4){0.f, 0.f, 0.f, 0.f};
#pragma unroll
        for (int nf = 0; nf < 4; ++nf) {
            int node = m0 + nf * 16 + lr;
            node = (node < n) ? node : (n - 1);
#pragma unroll
            for (int kc = 0; kc < 8; ++kc) {
                int kb = kc * 32 + lk8;
                bf16x8 x;
                if (kb < 128)
                    x = *(const bf16x8*)(Fb + (size_t)node * 128 + kb);
                else
                    x = *(const bf16x8*)(Mb + (size_t)node * 128 + (kb - 128));
                acc[0][nf] = __builtin_amdgcn_mfma_f32_16x16x32_bf16(w1f[0][kc], x, acc[0][nf], 0, 0, 0);
                acc[1][nf] = __builtin_amdgcn_mfma_f32_16x16x32_bf16(w1f[1][kc], x, acc[1][nf], 0, 0, 0);
            }
        }
        // stage h: lane holds outs (w*32+of*16+rbase..+3) for node (nf*16+lr) -> b64 4-bit-swz writes
#pragma unroll
        for (int of = 0; of < 2; ++of)
#pragma unroll
            for (int nf = 0; nf < 4; ++nf) {
                int node = nf * 16 + lr;
                unsigned int ob = (unsigned int)((w * 32 + of * 16 + rbase) * 2);
                uint2 pk;
                pk.x = pack2bf(fmaxf(acc[of][nf][0], 0.f), fmaxf(acc[of][nf][1], 0.f));
                pk.y = pack2bf(fmaxf(acc[of][nf][2], 0.f), fmaxf(acc[of][nf][3], 0.f));
                *(uint2*)(smem + node * 256 + (ob ^ ((unsigned int)(node & 15) << 4))) = pk;
            }
        __syncthreads();  // hT complete

        // ---- phase 2: Z^T = Wc · h^T ----
        f32x4 acc2[2][4];
#pragma unroll
        for (int of = 0; of < 2; ++of)
#pragma unroll
            for (int nf = 0; nf < 4; ++nf) acc2[of][nf] = (f32x4){0.f, 0.f, 0.f, 0.f};
#pragma unroll
        for (int nf = 0; nf < 4; ++nf) {
            int node = nf * 16 + lr;
            unsigned int sw2 = (unsigned int)(node & 15) << 4;
#pragma unroll
            for (int kc = 0; kc < 4; ++kc) {
                unsigned int kbyte = (unsigned int)((kc * 32 + lk8) * 2);
                bf16x8 x = *(const bf16x8*)(smem + node * 256 + (kbyte ^ sw2));
                acc2[0][nf] = __builtin_amdgcn_mfma_f32_16x16x32_bf16(w2f[0][kc], x, acc2[0][nf], 0, 0, 0);
                acc2[1][nf] = __builtin_amdgcn_mfma_f32_16x16x32_bf16(w2f[1][kc], x, acc2[1][nf], 0, 0, 0);
            }
        }
        __syncthreads();  // all waves done reading hT; overlay zaT/zbT

        // stage Z: waves 0,1 -> Za (outs 0..63 bf16, [64][128B]); waves 2,3 -> Zb (outs 64..127 fp8)
        {
            unsigned char* zaT = smem;         // 8 KB
            unsigned char* zbT = smem + 8192;  // 4 KB
#pragma unroll
            for (int of = 0; of < 2; ++of)
#pragma unroll
                for (int nf = 0; nf < 4; ++nf) {
                    int node = nf * 16 + lr;
                    int out = w * 32 + of * 16 + rbase;
                    if (w < 2) {
                        uint2 pk;
                        pk.x = pack2bf(acc2[of][nf][0], acc2[of][nf][1]);
                        pk.y = pack2bf(acc2[of][nf][2], acc2[of][nf][3]);
                        unsigned int ob = (unsigned int)(out * 2);
                        *(uint2*)(zaT + node * 128 + (ob ^ ((unsigned int)(node & 7) << 4))) = pk;
                    } else {
                        unsigned int pk = fp8x4_enc(acc2[of][nf][0], acc2[of][nf][1],
                                                    acc2[of][nf][2], acc2[of][nf][3]);
                        unsigned int ob = (unsigned int)(out - 64);
                        *(unsigned int*)(zbT + node * 64 + (ob ^ ((unsigned int)(node & 3) << 4))) = pk;
                    }
                }
        }
        __syncthreads();

        // coalesced global stores (un-swizzling 16B chunks)
#pragma unroll
        for (int c = 0; c < 2; ++c) {  // Za: 512 x 16B
            int chunk = c * 256 + t;
            int row = chunk >> 3, cb = (chunk & 7) * 16;
            int grow = m0 + row;
            if (grow < n)
                *(uint4*)((unsigned char*)Za + (size_t)grow * 128 + cb) =
                    *(const uint4*)(smem + row * 128 + (cb ^ ((row & 7) << 4)));
        }
        {  // Zb: 256 x 16B
            int row = t >> 2, cb = (t & 3) * 16;
            int grow = m0 + row;
            if (grow < n)
                *(uint4*)(Zb8 + (size_t)grow * 64 + cb) =
                    *(const uint4*)(smem + 8192 + row * 64 + (cb ^ ((row & 3) << 4)));
        }
        __syncthreads();  // LDS reads of this tile's stores done before next tile's hT writes
    }
}

// ---------- agg2: out[v] = f32(Za[v]) + mean_u fp8(Zb[u]); quarter-wave per node ----------
__global__ __launch_bounds__(256) void agg2(const unsigned short* __restrict__ Za,
                                            const unsigned char* __restrict__ Zb8,
                                            const int* __restrict__ offs,
                                            const int* __restrict__ csr,
                                            float* __restrict__ out, int n) {
    int t = threadIdx.x;
    int q = t >> 4, cl = t & 15;
    int v = blockIdx.x * 16 + q;
    if (v >= n) return;
    int beg = offs[v], end = offs[v + 1];
    float a0 = 0.f, a1 = 0.f, a2 = 0.f, a3 = 0.f;
    int e = beg;
    for (; e + 7 < end; e += 8) {
        int s[8];
#pragma unroll
        for (int k = 0; k < 8; ++k) s[k] = csr[e + k];
        unsigned int d[8];
#pragma unroll
        for (int k = 0; k < 8; ++k)
            d[k] = *(const unsigned int*)(Zb8 + (size_t)s[k] * 64 + cl * 4);
#pragma unroll
        for (int k = 0; k < 8; ++k) {
            float x, y, z, u2;
            fp8x4_dec(d[k], x, y, z, u2);
            a0 += x; a1 += y; a2 += z; a3 += u2;
        }
    }
    for (; e < end; ++e) {
        unsigned int d0 = *(const unsigned int*)(Zb8 + (size_t)csr[e] * 64 + cl * 4);
        float x, y, z, u2;
        fp8x4_dec(d0, x, y, z, u2);
        a0 += x; a1 += y; a2 += z; a3 += u2;
    }
    int deg = end - beg;
    float inv = 1.0f / (float)(deg > 0 ? deg : 1);
    uint2 uz = *(const uint2*)((const unsigned char*)Za + (size_t)v * 128 + cl * 8);
    float4 o;
    o.x = bf2f((unsigned short)uz.x) + a0 * inv;
    o.y = bf2f((unsigned short)(uz.x >> 16)) + a1 * inv;
    o.z = bf2f((unsigned short)uz.y) + a2 * inv;
    o.w = bf2f((unsigned short)(uz.y >> 16)) + a3 * inv;
    *(float4*)(out + (size_t)v * 64 + cl * 4) = o;
}

extern "C" void kernel_launch(void* const* d_in, const int* in_sizes, int n_in,
                              void* d_out, int out_size, void* d_ws, size_t ws_size,
                              hipStream_t stream) {
    const float* feat = (const float*)d_in[0];
    const int* esrc = (const int*)d_in[1];
    const int* edst = (const int*)d_in[2];
    const float* W0 = (const float*)d_in[3];  // [128, 256]
    const float* W1 = (const float*)d_in[4];  // [64, 256]
    float* out = (float*)d_out;

    int n = in_sizes[0] / 128;  // 100000
    int E = in_sizes[1];        // 1600000
    int NB = (n + 511) >> 9;    // 196 buckets

    char* ws = (char*)d_ws;
    size_t off = 0;
    auto alloc = [&](size_t bytes) -> void* {
        void* p = ws + off;
        off += (bytes + 255) & ~(size_t)255;
        return p;
    };
    int* offs = (int*)alloc((size_t)(n + 1) * 4);
    int* csr = (int*)alloc((size_t)E * 4);
    int* gcur = (int*)alloc((size_t)NB * 4);
    unsigned int* pairs = (unsigned int*)alloc((size_t)NB * BCAP * 4);
    unsigned short* Wb1 = (unsigned short*)alloc((size_t)128 * 256 * 2);
    unsigned short* Wb2 = (unsigned short*)alloc((size_t)128 * 128 * 2);
    unsigned short* Fb = (unsigned short*)alloc((size_t)n * 128 * 2);
    unsigned char* Ff8 = (unsigned char*)alloc((size_t)n * 128);
    unsigned short* Mb = (unsigned short*)alloc((size_t)n * 128 * 2);
    unsigned short* Za = (unsigned short*)alloc((size_t)n * 64 * 2);
    unsigned char* Zb8 = (unsigned char*)alloc((size_t)n * 64);

    int pblocks = (E + 4095) / 4096;  // 391
    int cblocks = 640;
    int nquad = n * 32;

    hipMemsetAsync(gcur, 0, (size_t)NB * 4, stream);
    megaA<<<pblocks + cblocks + 24, 256, 0, stream>>>(esrc, edst, gcur, pairs, E, NB,
                                                      feat, Fb, Ff8, nquad,
                                                      W0, Wb1, W1, Wb2, pblocks, cblocks);
    build<<<NB, 256, 0, stream>>>(pairs, gcur, offs, csr, n, NB, E);

    agg1<<<(n + 15) / 16, 256, 0, stream>>>(Ff8, offs, csr, Mb, n);
    int ntiles = (n + 63) / 64;  // 1563
    fused_gemm<<<(ntiles + 1) / 2, 256, 0, stream>>>(Fb, Mb, Wb1, Wb2, Za, Zb8, n, ntiles);
    agg2<<<(n + 15) / 16, 256, 0, stream>>>(Za, Zb8, offs, csr, out, n);
}

// Round 13
// 180.041 us; speedup vs baseline: 1.0600x; 1.0056x over previous
//
#include <hip/hip_runtime.h>
#include <hip/hip_bf16.h>

typedef __attribute__((ext_vector_type(8))) short bf16x8;
typedef __attribute__((ext_vector_type(4))) float f32x4;
typedef __attribute__((ext_vector_type(2))) float f32x2;

#define BSH 9       // nodes per bucket = 512
#define BCAP 12288  // per-bucket pair capacity (mean 8163, std ~90)

#if __has_builtin(__builtin_amdgcn_cvt_pk_f32_fp8) && __has_builtin(__builtin_amdgcn_cvt_pk_fp8_f32)
#define FP8_HW 1
#else
#define FP8_HW 0
#endif

// ---------- helpers ----------
__device__ __forceinline__ float bf2f(unsigned short u) {
    return __uint_as_float(((unsigned int)u) << 16);
}
__device__ __forceinline__ unsigned short f2bf(float f) {
    unsigned int u = __float_as_uint(f);
    unsigned int r = u + 0x7FFFu + ((u >> 16) & 1u);  // RNE
    return (unsigned short)(r >> 16);
}
__device__ __forceinline__ unsigned int pack2bf(float a, float b) {
    return (unsigned int)f2bf(a) | ((unsigned int)f2bf(b) << 16);
}

#if !FP8_HW
__device__ __forceinline__ unsigned int f2fp8_sw(float v) {
    unsigned int u = __float_as_uint(v);
    unsigned int s = (u >> 24) & 0x80u;
    unsigned int a = u & 0x7FFFFFFFu;
    float av = __uint_as_float(a);
    unsigned int q;
    if (av >= 0.015625f) {
        unsigned int r = a + 0x7FFFFu + ((a >> 20) & 1u);
        q = (r - (120u << 23)) >> 20;
        if (q > 0x7Eu) q = 0x7Eu;
    } else {
        q = (unsigned int)(av * 512.0f + 0.5f);
    }
    return s | q;
}
__device__ __forceinline__ float fp8_dec_sw(unsigned int u8) {
    unsigned int s = (u8 & 0x80u) << 24;
    unsigned int em = u8 & 0x7Fu;
    float vn = __uint_as_float(s | ((em << 20) + (120u << 23)));
    float vs = __uint_as_float(s | 0x3B000000u) * (float)(int)em;
    return em >= 8 ? vn : vs;
}
#endif

__device__ __forceinline__ void fp8x4_dec(unsigned int d, float& x, float& y, float& z, float& w) {
#if FP8_HW
    f32x2 lo = __builtin_amdgcn_cvt_pk_f32_fp8((int)d, false);
    f32x2 hi = __builtin_amdgcn_cvt_pk_f32_fp8((int)d, true);
    x = lo.x; y = lo.y; z = hi.x; w = hi.y;
#else
    x = fp8_dec_sw(d & 0xFFu);
    y = fp8_dec_sw((d >> 8) & 0xFFu);
    z = fp8_dec_sw((d >> 16) & 0xFFu);
    w = fp8_dec_sw((d >> 24) & 0xFFu);
#endif
}
__device__ __forceinline__ unsigned int fp8x4_enc(float a, float b, float c, float d) {
#if FP8_HW
    int u = __builtin_amdgcn_cvt_pk_fp8_f32(a, b, 0, false);
    u = __builtin_amdgcn_cvt_pk_fp8_f32(c, d, u, true);
    return (unsigned int)u;
#else
    return f2fp8_sw(a) | (f2fp8_sw(b) << 8) | (f2fp8_sw(c) << 16) | (f2fp8_sw(d) << 24);
#endif
}

// ---------- megaA: partition + feat conv (bf16 + fp8) + weight conv ----------
__global__ __launch_bounds__(256) void megaA(const int* __restrict__ esrc, const int* __restrict__ edst,
                                             int* __restrict__ gcur, unsigned int* __restrict__ pairs,
                                             int E, int NB,
                                             const float* __restrict__ feat, unsigned short* __restrict__ Fb,
                                             unsigned char* __restrict__ Ff8, int nquad,
                                             const float* __restrict__ W0, unsigned short* __restrict__ Wb1,
                                             const float* __restrict__ W1, unsigned short* __restrict__ Wb2,
                                             int pblocks, int cblocks) {
    __shared__ int bcnt[256];
    __shared__ int bbas[256];
    int b = blockIdx.x, t = threadIdx.x;
    if (b < pblocks) {
        int e0 = b * 4096;
        int eend = min(e0 + 4096, E);
        if (t < NB) bcnt[t] = 0;
        __syncthreads();
        for (int e = e0 + t; e < eend; e += 256) atomicAdd(&bcnt[edst[e] >> BSH], 1);
        __syncthreads();
        if (t < NB) {
            bbas[t] = t * BCAP + atomicAdd(&gcur[t], bcnt[t]);
            bcnt[t] = 0;
        }
        __syncthreads();
        for (int e = e0 + t; e < eend; e += 256) {
            int d = edst[e];
            int s = esrc[e];
            int bk = d >> BSH;
            int off = atomicAdd(&bcnt[bk], 1);
            pairs[bbas[bk] + off] = (unsigned int)s | ((unsigned int)(d & ((1 << BSH) - 1)) << 17);
        }
    } else if (b < pblocks + cblocks) {
        int cb = b - pblocks;
        for (int q = cb * 256 + t; q < nquad; q += cblocks * 256) {
            float4 f = *(const float4*)(feat + (size_t)q * 4);
            ushort4 ub;
            ub.x = f2bf(f.x); ub.y = f2bf(f.y); ub.z = f2bf(f.z); ub.w = f2bf(f.w);
            *(ushort4*)(Fb + (size_t)q * 4) = ub;
            *(unsigned int*)(Ff8 + (size_t)q * 4) = fp8x4_enc(f.x, f.y, f.z, f.w);
        }
    } else {
        int wb = b - pblocks - cblocks;
        for (int i = wb * 256 + t; i < 49152; i += 24 * 256) {
            if (i < 32768) {
                Wb1[i] = f2bf(W0[i]);
            } else {
                int i2 = i - 32768;
                int j = i2 >> 7, k = i2 & 127;
                float vv = (j < 64) ? W1[j * 256 + k] : W1[(j - 64) * 256 + 128 + k];
                Wb2[i2] = f2bf(vv);
            }
        }
    }
}

// ---------- build: in-block bucket scan + per-node offsets + csr placement ----------
__global__ __launch_bounds__(256) void build(const unsigned int* __restrict__ pairs,
                                             const int* __restrict__ gcur,
                                             int* __restrict__ offs, int* __restrict__ csr,
                                             int n, int NB, int E) {
    __shared__ int cnt[512];
    __shared__ int excl[512];
    __shared__ int wsum[4];
    __shared__ int woff[4];
    __shared__ int sbase;
    int b = blockIdx.x, t = threadIdx.x, lane = t & 63, wv = t >> 6;

    {
        int vv = (t < NB) ? gcur[t] : 0;
        int x = vv;
#pragma unroll
        for (int o = 1; o < 64; o <<= 1) {
            int y = __shfl_up(x, o, 64);
            if (lane >= o) x += y;
        }
        if (lane == 63) wsum[wv] = x;
        __syncthreads();
        if (t == 0) {
            int r = 0;
            for (int w = 0; w < 4; ++w) { woff[w] = r; r += wsum[w]; }
        }
        __syncthreads();
        if (t == b) sbase = woff[wv] + x - vv;
        if (b == 0 && t == 0) offs[n] = E;
    }
    __syncthreads();
    int base = sbase;
    int p0 = b * BCAP;
    int m = gcur[b];
    int v0 = b << BSH;

    cnt[t] = 0;
    cnt[t + 256] = 0;
    __syncthreads();
    for (int i = t; i < m; i += 256) atomicAdd(&cnt[pairs[p0 + i] >> 17], 1);
    __syncthreads();
    int c0 = cnt[2 * t], c1 = cnt[2 * t + 1];
    int s = c0 + c1;
    int x = s;
#pragma unroll
    for (int o = 1; o < 64; o <<= 1) {
        int y = __shfl_up(x, o, 64);
        if (lane >= o) x += y;
    }
    if (lane == 63) wsum[wv] = x;
    __syncthreads();
    if (t == 0) {
        int r = 0;
        for (int w = 0; w < 4; ++w) { woff[w] = r; r += wsum[w]; }
    }
    __syncthreads();
    int ex = woff[wv] + x - s;
    excl[2 * t] = ex;
    excl[2 * t + 1] = ex + c0;
    int v = v0 + 2 * t;
    if (v + 1 < n) {
        int2 o2;
        o2.x = base + ex;
        o2.y = base + ex + c0;
        *(int2*)(offs + v) = o2;
    } else if (v < n) {
        offs[v] = base + ex;
    }
    cnt[t] = 0;
    cnt[t + 256] = 0;
    __syncthreads();
    for (int i = t; i < m; i += 256) {
        unsigned int u = pairs[p0 + i];
        int dl = u >> 17;
        int off = atomicAdd(&cnt[dl], 1);
        csr[base + excl[dl] + off] = (int)(u & 0x1FFFFu);
    }
}

// ---------- agg1: Mb[v] = mean_{u in N(v)} fp8(feat[u]) -> bf16 [n][128] ----------
// quarter-wave (16 lanes) per node: uint2 load = 8B/lane, 16 lanes = full 128B row.
// 8 edges in flight; low VGPR (32) for max occupancy (TLP > ILP here — R11 lesson).
__global__ __launch_bounds__(256) void agg1(const unsigned char* __restrict__ Ff8,
                                            const int* __restrict__ offs,
                                            const int* __restrict__ csr,
                                            unsigned short* __restrict__ Mb, int n) {
    int t = threadIdx.x;
    int q = t >> 4, cl = t & 15;
    int v = blockIdx.x * 16 + q;
    if (v >= n) return;
    int beg = offs[v], end = offs[v + 1];
    float a0 = 0.f, a1 = 0.f, a2 = 0.f, a3 = 0.f;
    float a4 = 0.f, a5 = 0.f, a6 = 0.f, a7 = 0.f;
    int e = beg;
    for (; e + 7 < end; e += 8) {
        int s[8];
#pragma unroll
        for (int k = 0; k < 8; ++k) s[k] = csr[e + k];
        uint2 d[8];
#pragma unroll
        for (int k = 0; k < 8; ++k)
            d[k] = *(const uint2*)(Ff8 + (size_t)s[k] * 128 + cl * 8);
#pragma unroll
        for (int k = 0; k < 8; ++k) {
            float x0, y0, z0, w0, x1, y1, z1, w1;
            fp8x4_dec(d[k].x, x0, y0, z0, w0);
            fp8x4_dec(d[k].y, x1, y1, z1, w1);
            a0 += x0; a1 += y0; a2 += z0; a3 += w0;
            a4 += x1; a5 += y1; a6 += z1; a7 += w1;
        }
    }
    for (; e < end; ++e) {
        uint2 d0 = *(const uint2*)(Ff8 + (size_t)csr[e] * 128 + cl * 8);
        float x0, y0, z0, w0, x1, y1, z1, w1;
        fp8x4_dec(d0.x, x0, y0, z0, w0);
        fp8x4_dec(d0.y, x1, y1, z1, w1);
        a0 += x0; a1 += y0; a2 += z0; a3 += w0;
        a4 += x1; a5 += y1; a6 += z1; a7 += w1;
    }
    int deg = end - beg;
    float inv = 1.0f / (float)(deg > 0 ? deg : 1);
    uint4 pk;
    pk.x = pack2bf(a0 * inv, a1 * inv);
    pk.y = pack2bf(a2 * inv, a3 * inv);
    pk.z = pack2bf(a4 * inv, a5 * inv);
    pk.w = pack2bf(a6 * inv, a7 * inv);
    *(uint4*)(Mb + (size_t)v * 128 + cl * 8) = pk;
}

// ---------- fused GEMM, W-stationary: wave w owns outs [w*32,w*32+32), all 64 nodes ----------
// 2 contiguous tiles per block (weight fragments amortized); 4-bit hT swizzle; 16 KB LDS overlay.
__global__ __launch_bounds__(256) void fused_gemm(const unsigned short* __restrict__ Fb,  // [n][128]
                                                  const unsigned short* __restrict__ Mb,  // [n][128]
                                                  const unsigned short* __restrict__ Wb1, // [128][256]
                                                  const unsigned short* __restrict__ Wc,  // [128][128]
                                                  unsigned short* __restrict__ Za,        // [n][64] bf16
                                                  unsigned char* __restrict__ Zb8,        // [n][64] fp8
                                                  int n, int ntiles) {
    __shared__ __align__(16) unsigned char smem[16384];  // hT [64][256B swz]; later zaT/zbT overlay
    int t = threadIdx.x, l = t & 63, w = t >> 6;
    int lr = l & 15;
    int lk8 = (l >> 4) * 8;
    int rbase = (l >> 4) * 4;

    // ---- load this wave's weight fragments ONCE (96 VGPR) ----
    bf16x8 w1f[2][8];
#pragma unroll
    for (int of = 0; of < 2; ++of)
#pragma unroll
        for (int kc = 0; kc < 8; ++kc)
            w1f[of][kc] = *(const bf16x8*)(Wb1 + (size_t)(w * 32 + of * 16 + lr) * 256 + kc * 32 + lk8);
    bf16x8 w2f[2][4];
#pragma unroll
    for (int of = 0; of < 2; ++of)
#pragma unroll
        for (int kc = 0; kc < 4; ++kc)
            w2f[of][kc] = *(const bf16x8*)(Wc + (size_t)(w * 32 + of * 16 + lr) * 128 + kc * 32 + lk8);

#pragma unroll 1
    for (int it = 0; it < 2; ++it) {
        int tile = blockIdx.x * 2 + it;
        if (tile >= ntiles) break;
        int m0 = tile * 64;

        // ---- phase 1: h^T = relu(Wb1 · cat^T); wave covers 4 node-frags ----
        f32x4 acc[2][4];
#pragma unroll
        for (int of = 0; of < 2; ++of)
#pragma unroll
            for (int nf = 0; nf < 4; ++nf) acc[of][nf] = (f32x4){0.f, 0.f, 0.f, 0.f};
#pragma unroll
        for (int nf = 0; nf < 4; ++nf) {
            int node = m0 + nf * 16 + lr;
            node = (node < n) ? node : (n - 1);
#pragma unroll
            for (int kc = 0; kc < 8; ++kc) {
                int kb = kc * 32 + lk8;
                bf16x8 x;
                if (kb < 128)
                    x = *(const bf16x8*)(Fb + (size_t)node * 128 + kb);
                else
                    x = *(const bf16x8*)(Mb + (size_t)node * 128 + (kb - 128));
                acc[0][nf] = __builtin_amdgcn_mfma_f32_16x16x32_bf16(w1f[0][kc], x, acc[0][nf], 0, 0, 0);
                acc[1][nf] = __builtin_amdgcn_mfma_f32_16x16x32_bf16(w1f[1][kc], x, acc[1][nf], 0, 0, 0);
            }
        }
        // stage h: lane holds outs (w*32+of*16+rbase..+3) for node (nf*16+lr) -> b64 4-bit-swz writes
#pragma unroll
        for (int of = 0; of < 2; ++of)
#pragma unroll
            for (int nf = 0; nf < 4; ++nf) {
                int node = nf * 16 + lr;
                unsigned int ob = (unsigned int)((w * 32 + of * 16 + rbase) * 2);
                uint2 pk;
                pk.x = pack2bf(fmaxf(acc[of][nf][0], 0.f), fmaxf(acc[of][nf][1], 0.f));
                pk.y = pack2bf(fmaxf(acc[of][nf][2], 0.f), fmaxf(acc[of][nf][3], 0.f));
                *(uint2*)(smem + node * 256 + (ob ^ ((unsigned int)(node & 15) << 4))) = pk;
            }
        __syncthreads();  // hT complete

        // ---- phase 2: Z^T = Wc · h^T ----
        f32x4 acc2[2][4];
#pragma unroll
        for (int of = 0; of < 2; ++of)
#pragma unroll
            for (int nf = 0; nf < 4; ++nf) acc2[of][nf] = (f32x4){0.f, 0.f, 0.f, 0.f};
#pragma unroll
        for (int nf = 0; nf < 4; ++nf) {
            int node = nf * 16 + lr;
            unsigned int sw2 = (unsigned int)(node & 15) << 4;
#pragma unroll
            for (int kc = 0; kc < 4; ++kc) {
                unsigned int kbyte = (unsigned int)((kc * 32 + lk8) * 2);
                bf16x8 x = *(const bf16x8*)(smem + node * 256 + (kbyte ^ sw2));
                acc2[0][nf] = __builtin_amdgcn_mfma_f32_16x16x32_bf16(w2f[0][kc], x, acc2[0][nf], 0, 0, 0);
                acc2[1][nf] = __builtin_amdgcn_mfma_f32_16x16x32_bf16(w2f[1][kc], x, acc2[1][nf], 0, 0, 0);
            }
        }
        __syncthreads();  // all waves done reading hT; overlay zaT/zbT

        // stage Z: waves 0,1 -> Za (outs 0..63 bf16, [64][128B]); waves 2,3 -> Zb (outs 64..127 fp8)
        {
            unsigned char* zaT = smem;         // 8 KB
            unsigned char* zbT = smem + 8192;  // 4 KB
#pragma unroll
            for (int of = 0; of < 2; ++of)
#pragma unroll
                for (int nf = 0; nf < 4; ++nf) {
                    int node = nf * 16 + lr;
                    int out = w * 32 + of * 16 + rbase;
                    if (w < 2) {
                        uint2 pk;
                        pk.x = pack2bf(acc2[of][nf][0], acc2[of][nf][1]);
                        pk.y = pack2bf(acc2[of][nf][2], acc2[of][nf][3]);
                        unsigned int ob = (unsigned int)(out * 2);
                        *(uint2*)(zaT + node * 128 + (ob ^ ((unsigned int)(node & 7) << 4))) = pk;
                    } else {
                        unsigned int pk = fp8x4_enc(acc2[of][nf][0], acc2[of][nf][1],
                                                    acc2[of][nf][2], acc2[of][nf][3]);
                        unsigned int ob = (unsigned int)(out - 64);
                        *(unsigned int*)(zbT + node * 64 + (ob ^ ((unsigned int)(node & 3) << 4))) = pk;
                    }
                }
        }
        __syncthreads();

        // coalesced global stores (un-swizzling 16B chunks)
#pragma unroll
        for (int c = 0; c < 2; ++c) {  // Za: 512 x 16B
            int chunk = c * 256 + t;
            int row = chunk >> 3, cb = (chunk & 7) * 16;
            int grow = m0 + row;
            if (grow < n)
                *(uint4*)((unsigned char*)Za + (size_t)grow * 128 + cb) =
                    *(const uint4*)(smem + row * 128 + (cb ^ ((row & 7) << 4)));
        }
        {  // Zb: 256 x 16B
            int row = t >> 2, cb = (t & 3) * 16;
            int grow = m0 + row;
            if (grow < n)
                *(uint4*)(Zb8 + (size_t)grow * 64 + cb) =
                    *(const uint4*)(smem + 8192 + row * 64 + (cb ^ ((row & 3) << 4)));
        }
        __syncthreads();  // LDS reads of this tile's stores done before next tile's hT writes
    }
}

// ---------- agg2: out[v] = f32(Za[v]) + mean_u fp8(Zb[u]); quarter-wave per node ----------
__global__ __launch_bounds__(256) void agg2(const unsigned short* __restrict__ Za,
                                            const unsigned char* __restrict__ Zb8,
                                            const int* __restrict__ offs,
                                            const int* __restrict__ csr,
                                            float* __restrict__ out, int n) {
    int t = threadIdx.x;
    int q = t >> 4, cl = t & 15;
    int v = blockIdx.x * 16 + q;
    if (v >= n) return;
    int beg = offs[v], end = offs[v + 1];
    float a0 = 0.f, a1 = 0.f, a2 = 0.f, a3 = 0.f;
    int e = beg;
    for (; e + 7 < end; e += 8) {
        int s[8];
#pragma unroll
        for (int k = 0; k < 8; ++k) s[k] = csr[e + k];
        unsigned int d[8];
#pragma unroll
        for (int k = 0; k < 8; ++k)
            d[k] = *(const unsigned int*)(Zb8 + (size_t)s[k] * 64 + cl * 4);
#pragma unroll
        for (int k = 0; k < 8; ++k) {
            float x, y, z, u2;
            fp8x4_dec(d[k], x, y, z, u2);
            a0 += x; a1 += y; a2 += z; a3 += u2;
        }
    }
    for (; e < end; ++e) {
        unsigned int d0 = *(const unsigned int*)(Zb8 + (size_t)csr[e] * 64 + cl * 4);
        float x, y, z, u2;
        fp8x4_dec(d0, x, y, z, u2);
        a0 += x; a1 += y; a2 += z; a3 += u2;
    }
    int deg = end - beg;
    float inv = 1.0f / (float)(deg > 0 ? deg : 1);
    uint2 uz = *(const uint2*)((const unsigned char*)Za + (size_t)v * 128 + cl * 8);
    float4 o;
    o.x = bf2f((unsigned short)uz.x) + a0 * inv;
    o.y = bf2f((unsigned short)(uz.x >> 16)) + a1 * inv;
    o.z = bf2f((unsigned short)uz.y) + a2 * inv;
    o.w = bf2f((unsigned short)(uz.y >> 16)) + a3 * inv;
    *(float4*)(out + (size_t)v * 64 + cl * 4) = o;
}

extern "C" void kernel_launch(void* const* d_in, const int* in_sizes, int n_in,
                              void* d_out, int out_size, void* d_ws, size_t ws_size,
                              hipStream_t stream) {
    const float* feat = (const float*)d_in[0];
    const int* esrc = (const int*)d_in[1];
    const int* edst = (const int*)d_in[2];
    const float* W0 = (const float*)d_in[3];  // [128, 256]
    const float* W1 = (const float*)d_in[4];  // [64, 256]
    float* out = (float*)d_out;

    int n = in_sizes[0] / 128;  // 100000
    int E = in_sizes[1];        // 1600000
    int NB = (n + 511) >> 9;    // 196 buckets

    char* ws = (char*)d_ws;
    size_t off = 0;
    auto alloc = [&](size_t bytes) -> void* {
        void* p = ws + off;
        off += (bytes + 255) & ~(size_t)255;
        return p;
    };
    int* offs = (int*)alloc((size_t)(n + 1) * 4);
    int* csr = (int*)alloc((size_t)E * 4);
    int* gcur = (int*)alloc((size_t)NB * 4);
    unsigned int* pairs = (unsigned int*)alloc((size_t)NB * BCAP * 4);
    unsigned short* Wb1 = (unsigned short*)alloc((size_t)128 * 256 * 2);
    unsigned short* Wb2 = (unsigned short*)alloc((size_t)128 * 128 * 2);
    unsigned short* Fb = (unsigned short*)alloc((size_t)n * 128 * 2);
    unsigned char* Ff8 = (unsigned char*)alloc((size_t)n * 128);
    unsigned short* Mb = (unsigned short*)alloc((size_t)n * 128 * 2);
    unsigned short* Za = (unsigned short*)alloc((size_t)n * 64 * 2);
    unsigned char* Zb8 = (unsigned char*)alloc((size_t)n * 64);

    int pblocks = (E + 4095) / 4096;  // 391
    int cblocks = 640;
    int nquad = n * 32;

    hipMemsetAsync(gcur, 0, (size_t)NB * 4, stream);
    megaA<<<pblocks + cblocks + 24, 256, 0, stream>>>(esrc, edst, gcur, pairs, E, NB,
                                                      feat, Fb, Ff8, nquad,
                                                      W0, Wb1, W1, Wb2, pblocks, cblocks);
    build<<<NB, 256, 0, stream>>>(pairs, gcur, offs, csr, n, NB, E);

    agg1<<<(n + 15) / 16, 256, 0, stream>>>(Ff8, offs, csr, Mb, n);
    int ntiles = (n + 63) / 64;  // 1563
    fused_gemm<<<(ntiles + 1) / 2, 256, 0, stream>>>(Fb, Mb, Wb1, Wb2, Za, Zb8, n, ntiles);
    agg2<<<(n + 15) / 16, 256, 0, stream>>>(Za, Zb8, offs, csr, out, n);
}

// Round 14
// 158.587 us; speedup vs baseline: 1.2035x; 1.1353x over previous
//
#include <hip/hip_runtime.h>
#include <hip/hip_bf16.h>

typedef __attribute__((ext_vector_type(8))) short bf16x8;
typedef __attribute__((ext_vector_type(4))) float f32x4;
typedef __attribute__((ext_vector_type(2))) float f32x2;

#define BSH 9       // nodes per bucket = 512
#define BCAP 12288  // per-bucket pair capacity (mean 8163, std ~90)

#if __has_builtin(__builtin_amdgcn_cvt_pk_f32_fp8) && __has_builtin(__builtin_amdgcn_cvt_pk_fp8_f32)
#define FP8_HW 1
#else
#define FP8_HW 0
#endif

// ---------- helpers ----------
__device__ __forceinline__ float bf2f(unsigned short u) {
    return __uint_as_float(((unsigned int)u) << 16);
}
__device__ __forceinline__ unsigned short f2bf(float f) {
    unsigned int u = __float_as_uint(f);
    unsigned int r = u + 0x7FFFu + ((u >> 16) & 1u);  // RNE
    return (unsigned short)(r >> 16);
}
__device__ __forceinline__ unsigned int pack2bf(float a, float b) {
    return (unsigned int)f2bf(a) | ((unsigned int)f2bf(b) << 16);
}

#if !FP8_HW
__device__ __forceinline__ unsigned int f2fp8_sw(float v) {
    unsigned int u = __float_as_uint(v);
    unsigned int s = (u >> 24) & 0x80u;
    unsigned int a = u & 0x7FFFFFFFu;
    float av = __uint_as_float(a);
    unsigned int q;
    if (av >= 0.015625f) {
        unsigned int r = a + 0x7FFFFu + ((a >> 20) & 1u);
        q = (r - (120u << 23)) >> 20;
        if (q > 0x7Eu) q = 0x7Eu;
    } else {
        q = (unsigned int)(av * 512.0f + 0.5f);
    }
    return s | q;
}
__device__ __forceinline__ float fp8_dec_sw(unsigned int u8) {
    unsigned int s = (u8 & 0x80u) << 24;
    unsigned int em = u8 & 0x7Fu;
    float vn = __uint_as_float(s | ((em << 20) + (120u << 23)));
    float vs = __uint_as_float(s | 0x3B000000u) * (float)(int)em;
    return em >= 8 ? vn : vs;
}
#endif

__device__ __forceinline__ void fp8x4_dec(unsigned int d, float& x, float& y, float& z, float& w) {
#if FP8_HW
    f32x2 lo = __builtin_amdgcn_cvt_pk_f32_fp8((int)d, false);
    f32x2 hi = __builtin_amdgcn_cvt_pk_f32_fp8((int)d, true);
    x = lo.x; y = lo.y; z = hi.x; w = hi.y;
#else
    x = fp8_dec_sw(d & 0xFFu);
    y = fp8_dec_sw((d >> 8) & 0xFFu);
    z = fp8_dec_sw((d >> 16) & 0xFFu);
    w = fp8_dec_sw((d >> 24) & 0xFFu);
#endif
}
__device__ __forceinline__ unsigned int fp8x4_enc(float a, float b, float c, float d) {
#if FP8_HW
    int u = __builtin_amdgcn_cvt_pk_fp8_f32(a, b, 0, false);
    u = __builtin_amdgcn_cvt_pk_fp8_f32(c, d, u, true);
    return (unsigned int)u;
#else
    return f2fp8_sw(a) | (f2fp8_sw(b) << 8) | (f2fp8_sw(c) << 16) | (f2fp8_sw(d) << 24);
#endif
}

// ---------- megaA: partition + feat conv (bf16 + fp8) + weight conv + pad-row zeroing ----------
__global__ __launch_bounds__(256) void megaA(const int* __restrict__ esrc, const int* __restrict__ edst,
                                             int* __restrict__ gcur, unsigned int* __restrict__ pairs,
                                             int E, int NB,
                                             const float* __restrict__ feat, unsigned short* __restrict__ Fb,
                                             unsigned char* __restrict__ Ff8, int nquad,
                                             const float* __restrict__ W0, unsigned short* __restrict__ Wb1,
                                             const float* __restrict__ W1, unsigned short* __restrict__ Wb2,
                                             unsigned char* __restrict__ Zb8, int n,
                                             int pblocks, int cblocks) {
    __shared__ int bcnt[256];
    __shared__ int bbas[256];
    int b = blockIdx.x, t = threadIdx.x;
    if (b < pblocks) {
        int e0 = b * 4096;
        int eend = min(e0 + 4096, E);
        if (t < NB) bcnt[t] = 0;
        __syncthreads();
        for (int e = e0 + t; e < eend; e += 256) atomicAdd(&bcnt[edst[e] >> BSH], 1);
        __syncthreads();
        if (t < NB) {
            bbas[t] = t * BCAP + atomicAdd(&gcur[t], bcnt[t]);
            bcnt[t] = 0;
        }
        __syncthreads();
        for (int e = e0 + t; e < eend; e += 256) {
            int d = edst[e];
            int s = esrc[e];
            int bk = d >> BSH;
            int off = atomicAdd(&bcnt[bk], 1);
            pairs[bbas[bk] + off] = (unsigned int)s | ((unsigned int)(d & ((1 << BSH) - 1)) << 17);
        }
    } else if (b < pblocks + cblocks) {
        int cb = b - pblocks;
        if (cb == 0) {  // zero the pad rows (index n) used by branch-free agg tails
            if (t < 32) *(unsigned int*)(Ff8 + (size_t)n * 128 + t * 4) = 0u;
            else if (t < 48) *(unsigned int*)(Zb8 + (size_t)n * 64 + (t - 32) * 4) = 0u;
        }
        for (int q = cb * 256 + t; q < nquad; q += cblocks * 256) {
            float4 f = *(const float4*)(feat + (size_t)q * 4);
            ushort4 ub;
            ub.x = f2bf(f.x); ub.y = f2bf(f.y); ub.z = f2bf(f.z); ub.w = f2bf(f.w);
            *(ushort4*)(Fb + (size_t)q * 4) = ub;
            *(unsigned int*)(Ff8 + (size_t)q * 4) = fp8x4_enc(f.x, f.y, f.z, f.w);
        }
    } else {
        int wb = b - pblocks - cblocks;
        for (int i = wb * 256 + t; i < 49152; i += 24 * 256) {
            if (i < 32768) {
                Wb1[i] = f2bf(W0[i]);
            } else {
                int i2 = i - 32768;
                int j = i2 >> 7, k = i2 & 127;
                float vv = (j < 64) ? W1[j * 256 + k] : W1[(j - 64) * 256 + 128 + k];
                Wb2[i2] = f2bf(vv);
            }
        }
    }
}

// ---------- build: in-block bucket scan + per-node offsets + csr placement ----------
__global__ __launch_bounds__(256) void build(const unsigned int* __restrict__ pairs,
                                             const int* __restrict__ gcur,
                                             int* __restrict__ offs, int* __restrict__ csr,
                                             int n, int NB, int E) {
    __shared__ int cnt[512];
    __shared__ int excl[512];
    __shared__ int wsum[4];
    __shared__ int woff[4];
    __shared__ int sbase;
    int b = blockIdx.x, t = threadIdx.x, lane = t & 63, wv = t >> 6;

    {
        int vv = (t < NB) ? gcur[t] : 0;
        int x = vv;
#pragma unroll
        for (int o = 1; o < 64; o <<= 1) {
            int y = __shfl_up(x, o, 64);
            if (lane >= o) x += y;
        }
        if (lane == 63) wsum[wv] = x;
        __syncthreads();
        if (t == 0) {
            int r = 0;
            for (int w = 0; w < 4; ++w) { woff[w] = r; r += wsum[w]; }
        }
        __syncthreads();
        if (t == b) sbase = woff[wv] + x - vv;
        if (b == 0 && t == 0) offs[n] = E;
    }
    __syncthreads();
    int base = sbase;
    int p0 = b * BCAP;
    int m = gcur[b];
    int v0 = b << BSH;

    cnt[t] = 0;
    cnt[t + 256] = 0;
    __syncthreads();
    for (int i = t; i < m; i += 256) atomicAdd(&cnt[pairs[p0 + i] >> 17], 1);
    __syncthreads();
    int c0 = cnt[2 * t], c1 = cnt[2 * t + 1];
    int s = c0 + c1;
    int x = s;
#pragma unroll
    for (int o = 1; o < 64; o <<= 1) {
        int y = __shfl_up(x, o, 64);
        if (lane >= o) x += y;
    }
    if (lane == 63) wsum[wv] = x;
    __syncthreads();
    if (t == 0) {
        int r = 0;
        for (int w = 0; w < 4; ++w) { woff[w] = r; r += wsum[w]; }
    }
    __syncthreads();
    int ex = woff[wv] + x - s;
    excl[2 * t] = ex;
    excl[2 * t + 1] = ex + c0;
    int v = v0 + 2 * t;
    if (v + 1 < n) {
        int2 o2;
        o2.x = base + ex;
        o2.y = base + ex + c0;
        *(int2*)(offs + v) = o2;
    } else if (v < n) {
        offs[v] = base + ex;
    }
    cnt[t] = 0;
    cnt[t + 256] = 0;
    __syncthreads();
    for (int i = t; i < m; i += 256) {
        unsigned int u = pairs[p0 + i];
        int dl = u >> 17;
        int off = atomicAdd(&cnt[dl], 1);
        csr[base + excl[dl] + off] = (int)(u & 0x1FFFFu);
    }
}

// ---------- agg1: Mb[v] = mean_{u in N(v)} fp8(feat[u]) -> bf16 [n][128] ----------
// quarter-wave (16 lanes) per node; branch-free 8-deep loop (tail slots -> zero row n).
__global__ __launch_bounds__(256) void agg1(const unsigned char* __restrict__ Ff8,
                                            const int* __restrict__ offs,
                                            const int* __restrict__ csr,
                                            unsigned short* __restrict__ Mb, int n) {
    int t = threadIdx.x;
    int q = t >> 4, cl = t & 15;
    int v = blockIdx.x * 16 + q;
    if (v >= n) return;
    int beg = offs[v], end = offs[v + 1];
    float a0 = 0.f, a1 = 0.f, a2 = 0.f, a3 = 0.f;
    float a4 = 0.f, a5 = 0.f, a6 = 0.f, a7 = 0.f;
    for (int e = beg; e < end; e += 8) {
        int s[8];
#pragma unroll
        for (int k = 0; k < 8; ++k) {
            int idx = e + k;
            s[k] = (idx < end) ? csr[idx] : n;  // zero row for tail slots
        }
        uint2 d[8];
#pragma unroll
        for (int k = 0; k < 8; ++k)
            d[k] = *(const uint2*)(Ff8 + (size_t)s[k] * 128 + cl * 8);
#pragma unroll
        for (int k = 0; k < 8; ++k) {
            float x0, y0, z0, w0, x1, y1, z1, w1;
            fp8x4_dec(d[k].x, x0, y0, z0, w0);
            fp8x4_dec(d[k].y, x1, y1, z1, w1);
            a0 += x0; a1 += y0; a2 += z0; a3 += w0;
            a4 += x1; a5 += y1; a6 += z1; a7 += w1;
        }
    }
    int deg = end - beg;
    float inv = 1.0f / (float)(deg > 0 ? deg : 1);
    uint4 pk;
    pk.x = pack2bf(a0 * inv, a1 * inv);
    pk.y = pack2bf(a2 * inv, a3 * inv);
    pk.z = pack2bf(a4 * inv, a5 * inv);
    pk.w = pack2bf(a6 * inv, a7 * inv);
    *(uint4*)(Mb + (size_t)v * 128 + cl * 8) = pk;
}

// ---------- fused GEMM, W-stationary: wave w owns outs [w*32,w*32+32), all 64 nodes ----------
// 2 contiguous tiles per block (weight fragments amortized); 4-bit hT swizzle; 16 KB LDS overlay.
__global__ __launch_bounds__(256) void fused_gemm(const unsigned short* __restrict__ Fb,  // [n][128]
                                                  const unsigned short* __restrict__ Mb,  // [n][128]
                                                  const unsigned short* __restrict__ Wb1, // [128][256]
                                                  const unsigned short* __restrict__ Wc,  // [128][128]
                                                  unsigned short* __restrict__ Za,        // [n][64] bf16
                                                  unsigned char* __restrict__ Zb8,        // [n][64] fp8
                                                  int n, int ntiles) {
    __shared__ __align__(16) unsigned char smem[16384];  // hT [64][256B swz]; later zaT/zbT overlay
    int t = threadIdx.x, l = t & 63, w = t >> 6;
    int lr = l & 15;
    int lk8 = (l >> 4) * 8;
    int rbase = (l >> 4) * 4;

    // ---- load this wave's weight fragments ONCE (96 VGPR) ----
    bf16x8 w1f[2][8];
#pragma unroll
    for (int of = 0; of < 2; ++of)
#pragma unroll
        for (int kc = 0; kc < 8; ++kc)
            w1f[of][kc] = *(const bf16x8*)(Wb1 + (size_t)(w * 32 + of * 16 + lr) * 256 + kc * 32 + lk8);
    bf16x8 w2f[2][4];
#pragma unroll
    for (int of = 0; of < 2; ++of)
#pragma unroll
        for (int kc = 0; kc < 4; ++kc)
            w2f[of][kc] = *(const bf16x8*)(Wc + (size_t)(w * 32 + of * 16 + lr) * 128 + kc * 32 + lk8);

#pragma unroll 1
    for (int it = 0; it < 2; ++it) {
        int tile = blockIdx.x * 2 + it;
        if (tile >= ntiles) break;
        int m0 = tile * 64;

        // ---- phase 1: h^T = relu(Wb1 · cat^T); wave covers 4 node-frags ----
        f32x4 acc[2][4];
#pragma unroll
        for (int of = 0; of < 2; ++of)
#pragma unroll
            for (int nf = 0; nf < 4; ++nf) acc[of][nf] = (f32x4){0.f, 0.f, 0.f, 0.f};
#pragma unroll
        for (int nf = 0; nf < 4; ++nf) {
            int node = m0 + nf * 16 + lr;
            node = (node < n) ? node : (n - 1);
#pragma unroll
            for (int kc = 0; kc < 8; ++kc) {
                int kb = kc * 32 + lk8;
                bf16x8 x;
                if (kb < 128)
                    x = *(const bf16x8*)(Fb + (size_t)node * 128 + kb);
                else
                    x = *(const bf16x8*)(Mb + (size_t)node * 128 + (kb - 128));
                acc[0][nf] = __builtin_amdgcn_mfma_f32_16x16x32_bf16(w1f[0][kc], x, acc[0][nf], 0, 0, 0);
                acc[1][nf] = __builtin_amdgcn_mfma_f32_16x16x32_bf16(w1f[1][kc], x, acc[1][nf], 0, 0, 0);
            }
        }
        // stage h: lane holds outs (w*32+of*16+rbase..+3) for node (nf*16+lr) -> b64 4-bit-swz writes
#pragma unroll
        for (int of = 0; of < 2; ++of)
#pragma unroll
            for (int nf = 0; nf < 4; ++nf) {
                int node = nf * 16 + lr;
                unsigned int ob = (unsigned int)((w * 32 + of * 16 + rbase) * 2);
                uint2 pk;
                pk.x = pack2bf(fmaxf(acc[of][nf][0], 0.f), fmaxf(acc[of][nf][1], 0.f));
                pk.y = pack2bf(fmaxf(acc[of][nf][2], 0.f), fmaxf(acc[of][nf][3], 0.f));
                *(uint2*)(smem + node * 256 + (ob ^ ((unsigned int)(node & 15) << 4))) = pk;
            }
        __syncthreads();  // hT complete

        // ---- phase 2: Z^T = Wc · h^T ----
        f32x4 acc2[2][4];
#pragma unroll
        for (int of = 0; of < 2; ++of)
#pragma unroll
            for (int nf = 0; nf < 4; ++nf) acc2[of][nf] = (f32x4){0.f, 0.f, 0.f, 0.f};
#pragma unroll
        for (int nf = 0; nf < 4; ++nf) {
            int node = nf * 16 + lr;
            unsigned int sw2 = (unsigned int)(node & 15) << 4;
#pragma unroll
            for (int kc = 0; kc < 4; ++kc) {
                unsigned int kbyte = (unsigned int)((kc * 32 + lk8) * 2);
                bf16x8 x = *(const bf16x8*)(smem + node * 256 + (kbyte ^ sw2));
                acc2[0][nf] = __builtin_amdgcn_mfma_f32_16x16x32_bf16(w2f[0][kc], x, acc2[0][nf], 0, 0, 0);
                acc2[1][nf] = __builtin_amdgcn_mfma_f32_16x16x32_bf16(w2f[1][kc], x, acc2[1][nf], 0, 0, 0);
            }
        }
        __syncthreads();  // all waves done reading hT; overlay zaT/zbT

        // stage Z: waves 0,1 -> Za (outs 0..63 bf16, [64][128B]); waves 2,3 -> Zb (outs 64..127 fp8)
        {
            unsigned char* zaT = smem;         // 8 KB
            unsigned char* zbT = smem + 8192;  // 4 KB
#pragma unroll
            for (int of = 0; of < 2; ++of)
#pragma unroll
                for (int nf = 0; nf < 4; ++nf) {
                    int node = nf * 16 + lr;
                    int out = w * 32 + of * 16 + rbase;
                    if (w < 2) {
                        uint2 pk;
                        pk.x = pack2bf(acc2[of][nf][0], acc2[of][nf][1]);
                        pk.y = pack2bf(acc2[of][nf][2], acc2[of][nf][3]);
                        unsigned int ob = (unsigned int)(out * 2);
                        *(uint2*)(zaT + node * 128 + (ob ^ ((unsigned int)(node & 7) << 4))) = pk;
                    } else {
                        unsigned int pk = fp8x4_enc(acc2[of][nf][0], acc2[of][nf][1],
                                                    acc2[of][nf][2], acc2[of][nf][3]);
                        unsigned int ob = (unsigned int)(out - 64);
                        *(unsigned int*)(zbT + node * 64 + (ob ^ ((unsigned int)(node & 3) << 4))) = pk;
                    }
                }
        }
        __syncthreads();

        // coalesced global stores (un-swizzling 16B chunks)
#pragma unroll
        for (int c = 0; c < 2; ++c) {  // Za: 512 x 16B
            int chunk = c * 256 + t;
            int row = chunk >> 3, cb = (chunk & 7) * 16;
            int grow = m0 + row;
            if (grow < n)
                *(uint4*)((unsigned char*)Za + (size_t)grow * 128 + cb) =
                    *(const uint4*)(smem + row * 128 + (cb ^ ((row & 7) << 4)));
        }
        {  // Zb: 256 x 16B
            int row = t >> 2, cb = (t & 3) * 16;
            int grow = m0 + row;
            if (grow < n)
                *(uint4*)(Zb8 + (size_t)grow * 64 + cb) =
                    *(const uint4*)(smem + 8192 + row * 64 + (cb ^ ((row & 3) << 4)));
        }
        __syncthreads();  // LDS reads of this tile's stores done before next tile's hT writes
    }
}

// ---------- agg2: out[v] = f32(Za[v]) + mean_u fp8(Zb[u]); quarter-wave per node ----------
// branch-free 8-deep loop (tail slots -> zero row n of Zb8).
__global__ __launch_bounds__(256) void agg2(const unsigned short* __restrict__ Za,
                                            const unsigned char* __restrict__ Zb8,
                                            const int* __restrict__ offs,
                                            const int* __restrict__ csr,
                                            float* __restrict__ out, int n) {
    int t = threadIdx.x;
    int q = t >> 4, cl = t & 15;
    int v = blockIdx.x * 16 + q;
    if (v >= n) return;
    int beg = offs[v], end = offs[v + 1];
    float a0 = 0.f, a1 = 0.f, a2 = 0.f, a3 = 0.f;
    for (int e = beg; e < end; e += 8) {
        int s[8];
#pragma unroll
        for (int k = 0; k < 8; ++k) {
            int idx = e + k;
            s[k] = (idx < end) ? csr[idx] : n;  // zero row for tail slots
        }
        unsigned int d[8];
#pragma unroll
        for (int k = 0; k < 8; ++k)
            d[k] = *(const unsigned int*)(Zb8 + (size_t)s[k] * 64 + cl * 4);
#pragma unroll
        for (int k = 0; k < 8; ++k) {
            float x, y, z, u2;
            fp8x4_dec(d[k], x, y, z, u2);
            a0 += x; a1 += y; a2 += z; a3 += u2;
        }
    }
    int deg = end - beg;
    float inv = 1.0f / (float)(deg > 0 ? deg : 1);
    uint2 uz = *(const uint2*)((const unsigned char*)Za + (size_t)v * 128 + cl * 8);
    float4 o;
    o.x = bf2f((unsigned short)uz.x) + a0 * inv;
    o.y = bf2f((unsigned short)(uz.x >> 16)) + a1 * inv;
    o.z = bf2f((unsigned short)uz.y) + a2 * inv;
    o.w = bf2f((unsigned short)(uz.y >> 16)) + a3 * inv;
    *(float4*)(out + (size_t)v * 64 + cl * 4) = o;
}

extern "C" void kernel_launch(void* const* d_in, const int* in_sizes, int n_in,
                              void* d_out, int out_size, void* d_ws, size_t ws_size,
                              hipStream_t stream) {
    const float* feat = (const float*)d_in[0];
    const int* esrc = (const int*)d_in[1];
    const int* edst = (const int*)d_in[2];
    const float* W0 = (const float*)d_in[3];  // [128, 256]
    const float* W1 = (const float*)d_in[4];  // [64, 256]
    float* out = (float*)d_out;

    int n = in_sizes[0] / 128;  // 100000
    int E = in_sizes[1];        // 1600000
    int NB = (n + 511) >> 9;    // 196 buckets

    char* ws = (char*)d_ws;
    size_t off = 0;
    auto alloc = [&](size_t bytes) -> void* {
        void* p = ws + off;
        off += (bytes + 255) & ~(size_t)255;
        return p;
    };
    int* offs = (int*)alloc((size_t)(n + 1) * 4);
    int* csr = (int*)alloc((size_t)(E + 8) * 4);  // +8 slack for speculative tail reads
    int* gcur = (int*)alloc((size_t)NB * 4);
    unsigned int* pairs = (unsigned int*)alloc((size_t)NB * BCAP * 4);
    unsigned short* Wb1 = (unsigned short*)alloc((size_t)128 * 256 * 2);
    unsigned short* Wb2 = (unsigned short*)alloc((size_t)128 * 128 * 2);
    unsigned short* Fb = (unsigned short*)alloc((size_t)n * 128 * 2);
    unsigned char* Ff8 = (unsigned char*)alloc((size_t)(n + 1) * 128);  // +1 zero pad row
    unsigned short* Mb = (unsigned short*)alloc((size_t)n * 128 * 2);
    unsigned short* Za = (unsigned short*)alloc((size_t)n * 64 * 2);
    unsigned char* Zb8 = (unsigned char*)alloc((size_t)(n + 1) * 64);   // +1 zero pad row

    int pblocks = (E + 4095) / 4096;  // 391
    int cblocks = 640;
    int nquad = n * 32;

    hipMemsetAsync(gcur, 0, (size_t)NB * 4, stream);
    megaA<<<pblocks + cblocks + 24, 256, 0, stream>>>(esrc, edst, gcur, pairs, E, NB,
                                                      feat, Fb, Ff8, nquad,
                                                      W0, Wb1, W1, Wb2, Zb8, n, pblocks, cblocks);
    build<<<NB, 256, 0, stream>>>(pairs, gcur, offs, csr, n, NB, E);

    agg1<<<(n + 15) / 16, 256, 0, stream>>>(Ff8, offs, csr, Mb, n);
    int ntiles = (n + 63) / 64;  // 1563
    fused_gemm<<<(ntiles + 1) / 2, 256, 0, stream>>>(Fb, Mb, Wb1, Wb2, Za, Zb8, n, ntiles);
    agg2<<<(n + 15) / 16, 256, 0, stream>>>(Za, Zb8, offs, csr, out, n);
}

// Round 15
// 155.155 us; speedup vs baseline: 1.2301x; 1.0221x over previous
//
#include <hip/hip_runtime.h>
#include <hip/hip_bf16.h>

typedef __attribute__((ext_vector_type(8))) short bf16x8;
typedef __attribute__((ext_vector_type(4))) float f32x4;
typedef __attribute__((ext_vector_type(2))) float f32x2;

#define BSH 9       // nodes per bucket = 512
#define BCAP 12288  // per-bucket pair capacity (mean 8163, std ~90)

#if __has_builtin(__builtin_amdgcn_cvt_pk_f32_fp8) && __has_builtin(__builtin_amdgcn_cvt_pk_fp8_f32)
#define FP8_HW 1
#else
#define FP8_HW 0
#endif

// ---------- helpers ----------
__device__ __forceinline__ float bf2f(unsigned short u) {
    return __uint_as_float(((unsigned int)u) << 16);
}
__device__ __forceinline__ unsigned short f2bf(float f) {
    unsigned int u = __float_as_uint(f);
    unsigned int r = u + 0x7FFFu + ((u >> 16) & 1u);  // RNE
    return (unsigned short)(r >> 16);
}
__device__ __forceinline__ unsigned int pack2bf(float a, float b) {
    return (unsigned int)f2bf(a) | ((unsigned int)f2bf(b) << 16);
}

#if !FP8_HW
__device__ __forceinline__ unsigned int f2fp8_sw(float v) {
    unsigned int u = __float_as_uint(v);
    unsigned int s = (u >> 24) & 0x80u;
    unsigned int a = u & 0x7FFFFFFFu;
    float av = __uint_as_float(a);
    unsigned int q;
    if (av >= 0.015625f) {
        unsigned int r = a + 0x7FFFFu + ((a >> 20) & 1u);
        q = (r - (120u << 23)) >> 20;
        if (q > 0x7Eu) q = 0x7Eu;
    } else {
        q = (unsigned int)(av * 512.0f + 0.5f);
    }
    return s | q;
}
__device__ __forceinline__ float fp8_dec_sw(unsigned int u8) {
    unsigned int s = (u8 & 0x80u) << 24;
    unsigned int em = u8 & 0x7Fu;
    float vn = __uint_as_float(s | ((em << 20) + (120u << 23)));
    float vs = __uint_as_float(s | 0x3B000000u) * (float)(int)em;
    return em >= 8 ? vn : vs;
}
#endif

__device__ __forceinline__ void fp8x4_dec(unsigned int d, float& x, float& y, float& z, float& w) {
#if FP8_HW
    f32x2 lo = __builtin_amdgcn_cvt_pk_f32_fp8((int)d, false);
    f32x2 hi = __builtin_amdgcn_cvt_pk_f32_fp8((int)d, true);
    x = lo.x; y = lo.y; z = hi.x; w = hi.y;
#else
    x = fp8_dec_sw(d & 0xFFu);
    y = fp8_dec_sw((d >> 8) & 0xFFu);
    z = fp8_dec_sw((d >> 16) & 0xFFu);
    w = fp8_dec_sw((d >> 24) & 0xFFu);
#endif
}
__device__ __forceinline__ unsigned int fp8x4_enc(float a, float b, float c, float d) {
#if FP8_HW
    int u = __builtin_amdgcn_cvt_pk_fp8_f32(a, b, 0, false);
    u = __builtin_amdgcn_cvt_pk_fp8_f32(c, d, u, true);
    return (unsigned int)u;
#else
    return f2fp8_sw(a) | (f2fp8_sw(b) << 8) | (f2fp8_sw(c) << 16) | (f2fp8_sw(d) << 24);
#endif
}

// ---------- megaA: partition + feat conv (bf16 + fp8) + weight conv + pad-row zeroing ----------
__global__ __launch_bounds__(256) void megaA(const int* __restrict__ esrc, const int* __restrict__ edst,
                                             int* __restrict__ gcur, unsigned int* __restrict__ pairs,
                                             int E, int NB,
                                             const float* __restrict__ feat, unsigned short* __restrict__ Fb,
                                             unsigned char* __restrict__ Ff8, int nquad,
                                             const float* __restrict__ W0, unsigned short* __restrict__ Wb1,
                                             const float* __restrict__ W1, unsigned short* __restrict__ Wb2,
                                             unsigned char* __restrict__ Zb8, int n,
                                             int pblocks, int cblocks) {
    __shared__ int bcnt[256];
    __shared__ int bbas[256];
    int b = blockIdx.x, t = threadIdx.x;
    if (b < pblocks) {
        int e0 = b * 4096;
        int eend = min(e0 + 4096, E);
        if (t < NB) bcnt[t] = 0;
        __syncthreads();
        for (int e = e0 + t; e < eend; e += 256) atomicAdd(&bcnt[edst[e] >> BSH], 1);
        __syncthreads();
        if (t < NB) {
            bbas[t] = t * BCAP + atomicAdd(&gcur[t], bcnt[t]);
            bcnt[t] = 0;
        }
        __syncthreads();
        for (int e = e0 + t; e < eend; e += 256) {
            int d = edst[e];
            int s = esrc[e];
            int bk = d >> BSH;
            int off = atomicAdd(&bcnt[bk], 1);
            pairs[bbas[bk] + off] = (unsigned int)s | ((unsigned int)(d & ((1 << BSH) - 1)) << 17);
        }
    } else if (b < pblocks + cblocks) {
        int cb = b - pblocks;
        if (cb == 0) {  // zero the pad rows (index n) used by branch-free agg tails
            if (t < 32) *(unsigned int*)(Ff8 + (size_t)n * 128 + t * 4) = 0u;
            else if (t < 48) *(unsigned int*)(Zb8 + (size_t)n * 64 + (t - 32) * 4) = 0u;
        }
        for (int q = cb * 256 + t; q < nquad; q += cblocks * 256) {
            float4 f = *(const float4*)(feat + (size_t)q * 4);
            ushort4 ub;
            ub.x = f2bf(f.x); ub.y = f2bf(f.y); ub.z = f2bf(f.z); ub.w = f2bf(f.w);
            *(ushort4*)(Fb + (size_t)q * 4) = ub;
            *(unsigned int*)(Ff8 + (size_t)q * 4) = fp8x4_enc(f.x, f.y, f.z, f.w);
        }
    } else {
        int wb = b - pblocks - cblocks;
        for (int i = wb * 256 + t; i < 49152; i += 24 * 256) {
            if (i < 32768) {
                Wb1[i] = f2bf(W0[i]);
            } else {
                int i2 = i - 32768;
                int j = i2 >> 7, k = i2 & 127;
                float vv = (j < 64) ? W1[j * 256 + k] : W1[(j - 64) * 256 + 128 + k];
                Wb2[i2] = f2bf(vv);
            }
        }
    }
}

// ---------- build: in-block bucket scan + per-node offsets + csr placement ----------
__global__ __launch_bounds__(256) void build(const unsigned int* __restrict__ pairs,
                                             const int* __restrict__ gcur,
                                             int* __restrict__ offs, int* __restrict__ csr,
                                             int n, int NB, int E) {
    __shared__ int cnt[512];
    __shared__ int excl[512];
    __shared__ int wsum[4];
    __shared__ int woff[4];
    __shared__ int sbase;
    int b = blockIdx.x, t = threadIdx.x, lane = t & 63, wv = t >> 6;

    {
        int vv = (t < NB) ? gcur[t] : 0;
        int x = vv;
#pragma unroll
        for (int o = 1; o < 64; o <<= 1) {
            int y = __shfl_up(x, o, 64);
            if (lane >= o) x += y;
        }
        if (lane == 63) wsum[wv] = x;
        __syncthreads();
        if (t == 0) {
            int r = 0;
            for (int w = 0; w < 4; ++w) { woff[w] = r; r += wsum[w]; }
        }
        __syncthreads();
        if (t == b) sbase = woff[wv] + x - vv;
        if (b == 0 && t == 0) offs[n] = E;
    }
    __syncthreads();
    int base = sbase;
    int p0 = b * BCAP;
    int m = gcur[b];
    int v0 = b << BSH;

    cnt[t] = 0;
    cnt[t + 256] = 0;
    __syncthreads();
    for (int i = t; i < m; i += 256) atomicAdd(&cnt[pairs[p0 + i] >> 17], 1);
    __syncthreads();
    int c0 = cnt[2 * t], c1 = cnt[2 * t + 1];
    int s = c0 + c1;
    int x = s;
#pragma unroll
    for (int o = 1; o < 64; o <<= 1) {
        int y = __shfl_up(x, o, 64);
        if (lane >= o) x += y;
    }
    if (lane == 63) wsum[wv] = x;
    __syncthreads();
    if (t == 0) {
        int r = 0;
        for (int w = 0; w < 4; ++w) { woff[w] = r; r += wsum[w]; }
    }
    __syncthreads();
    int ex = woff[wv] + x - s;
    excl[2 * t] = ex;
    excl[2 * t + 1] = ex + c0;
    int v = v0 + 2 * t;
    if (v + 1 < n) {
        int2 o2;
        o2.x = base + ex;
        o2.y = base + ex + c0;
        *(int2*)(offs + v) = o2;
    } else if (v < n) {
        offs[v] = base + ex;
    }
    cnt[t] = 0;
    cnt[t + 256] = 0;
    __syncthreads();
    for (int i = t; i < m; i += 256) {
        unsigned int u = pairs[p0 + i];
        int dl = u >> 17;
        int off = atomicAdd(&cnt[dl], 1);
        csr[base + excl[dl] + off] = (int)(u & 0x1FFFFu);
    }
}

// ---------- agg1: Mb[v] = mean_{u in N(v)} fp8(feat[u]) -> bf16 [n][128] ----------
// quarter-wave (16 lanes) per node; branch-free 8-deep loop (tail slots -> zero row n).
__global__ __launch_bounds__(256) void agg1(const unsigned char* __restrict__ Ff8,
                                            const int* __restrict__ offs,
                                            const int* __restrict__ csr,
                                            unsigned short* __restrict__ Mb, int n) {
    int t = threadIdx.x;
    int q = t >> 4, cl = t & 15;
    int v = blockIdx.x * 16 + q;
    if (v >= n) return;
    int beg = offs[v], end = offs[v + 1];
    float a0 = 0.f, a1 = 0.f, a2 = 0.f, a3 = 0.f;
    float a4 = 0.f, a5 = 0.f, a6 = 0.f, a7 = 0.f;
    for (int e = beg; e < end; e += 8) {
        int s[8];
#pragma unroll
        for (int k = 0; k < 8; ++k) {
            int idx = e + k;
            s[k] = (idx < end) ? csr[idx] : n;  // zero row for tail slots
        }
        uint2 d[8];
#pragma unroll
        for (int k = 0; k < 8; ++k)
            d[k] = *(const uint2*)(Ff8 + (size_t)s[k] * 128 + cl * 8);
#pragma unroll
        for (int k = 0; k < 8; ++k) {
            float x0, y0, z0, w0, x1, y1, z1, w1;
            fp8x4_dec(d[k].x, x0, y0, z0, w0);
            fp8x4_dec(d[k].y, x1, y1, z1, w1);
            a0 += x0; a1 += y0; a2 += z0; a3 += w0;
            a4 += x1; a5 += y1; a6 += z1; a7 += w1;
        }
    }
    int deg = end - beg;
    float inv = 1.0f / (float)(deg > 0 ? deg : 1);
    uint4 pk;
    pk.x = pack2bf(a0 * inv, a1 * inv);
    pk.y = pack2bf(a2 * inv, a3 * inv);
    pk.z = pack2bf(a4 * inv, a5 * inv);
    pk.w = pack2bf(a6 * inv, a7 * inv);
    *(uint4*)(Mb + (size_t)v * 128 + cl * 8) = pk;
}

// ---------- fused GEMM, W-stationary: wave w owns outs [w*32,w*32+32), all 64 nodes ----------
// Grid-stride loop over tiles with grid = 4 blocks/CU (VGPR-allowed residency);
// loop structure keeps weight fragments register-resident. 4-bit hT swizzle; 16 KB LDS overlay.
__global__ __launch_bounds__(256) void fused_gemm(const unsigned short* __restrict__ Fb,  // [n][128]
                                                  const unsigned short* __restrict__ Mb,  // [n][128]
                                                  const unsigned short* __restrict__ Wb1, // [128][256]
                                                  const unsigned short* __restrict__ Wc,  // [128][128]
                                                  unsigned short* __restrict__ Za,        // [n][64] bf16
                                                  unsigned char* __restrict__ Zb8,        // [n][64] fp8
                                                  int n, int ntiles) {
    __shared__ __align__(16) unsigned char smem[16384];  // hT [64][256B swz]; later zaT/zbT overlay
    int t = threadIdx.x, l = t & 63, w = t >> 6;
    int lr = l & 15;
    int lk8 = (l >> 4) * 8;
    int rbase = (l >> 4) * 4;

    // ---- load this wave's weight fragments ONCE (96 VGPR) ----
    bf16x8 w1f[2][8];
#pragma unroll
    for (int of = 0; of < 2; ++of)
#pragma unroll
        for (int kc = 0; kc < 8; ++kc)
            w1f[of][kc] = *(const bf16x8*)(Wb1 + (size_t)(w * 32 + of * 16 + lr) * 256 + kc * 32 + lk8);
    bf16x8 w2f[2][4];
#pragma unroll
    for (int of = 0; of < 2; ++of)
#pragma unroll
        for (int kc = 0; kc < 4; ++kc)
            w2f[of][kc] = *(const bf16x8*)(Wc + (size_t)(w * 32 + of * 16 + lr) * 128 + kc * 32 + lk8);

#pragma unroll 1
    for (int tile = blockIdx.x; tile < ntiles; tile += gridDim.x) {
        int m0 = tile * 64;

        // ---- phase 1: h^T = relu(Wb1 · cat^T); wave covers 4 node-frags ----
        f32x4 acc[2][4];
#pragma unroll
        for (int of = 0; of < 2; ++of)
#pragma unroll
            for (int nf = 0; nf < 4; ++nf) acc[of][nf] = (f32x4){0.f, 0.f, 0.f, 0.f};
#pragma unroll
        for (int nf = 0; nf < 4; ++nf) {
            int node = m0 + nf * 16 + lr;
            node = (node < n) ? node : (n - 1);
#pragma unroll
            for (int kc = 0; kc < 8; ++kc) {
                int kb = kc * 32 + lk8;
                bf16x8 x;
                if (kb < 128)
                    x = *(const bf16x8*)(Fb + (size_t)node * 128 + kb);
                else
                    x = *(const bf16x8*)(Mb + (size_t)node * 128 + (kb - 128));
                acc[0][nf] = __builtin_amdgcn_mfma_f32_16x16x32_bf16(w1f[0][kc], x, acc[0][nf], 0, 0, 0);
                acc[1][nf] = __builtin_amdgcn_mfma_f32_16x16x32_bf16(w1f[1][kc], x, acc[1][nf], 0, 0, 0);
            }
        }
        // stage h: lane holds outs (w*32+of*16+rbase..+3) for node (nf*16+lr) -> b64 4-bit-swz writes
#pragma unroll
        for (int of = 0; of < 2; ++of)
#pragma unroll
            for (int nf = 0; nf < 4; ++nf) {
                int node = nf * 16 + lr;
                unsigned int ob = (unsigned int)((w * 32 + of * 16 + rbase) * 2);
                uint2 pk;
                pk.x = pack2bf(fmaxf(acc[of][nf][0], 0.f), fmaxf(acc[of][nf][1], 0.f));
                pk.y = pack2bf(fmaxf(acc[of][nf][2], 0.f), fmaxf(acc[of][nf][3], 0.f));
                *(uint2*)(smem + node * 256 + (ob ^ ((unsigned int)(node & 15) << 4))) = pk;
            }
        __syncthreads();  // hT complete

        // ---- phase 2: Z^T = Wc · h^T ----
        f32x4 acc2[2][4];
#pragma unroll
        for (int of = 0; of < 2; ++of)
#pragma unroll
            for (int nf = 0; nf < 4; ++nf) acc2[of][nf] = (f32x4){0.f, 0.f, 0.f, 0.f};
#pragma unroll
        for (int nf = 0; nf < 4; ++nf) {
            int node = nf * 16 + lr;
            unsigned int sw2 = (unsigned int)(node & 15) << 4;
#pragma unroll
            for (int kc = 0; kc < 4; ++kc) {
                unsigned int kbyte = (unsigned int)((kc * 32 + lk8) * 2);
                bf16x8 x = *(const bf16x8*)(smem + node * 256 + (kbyte ^ sw2));
                acc2[0][nf] = __builtin_amdgcn_mfma_f32_16x16x32_bf16(w2f[0][kc], x, acc2[0][nf], 0, 0, 0);
                acc2[1][nf] = __builtin_amdgcn_mfma_f32_16x16x32_bf16(w2f[1][kc], x, acc2[1][nf], 0, 0, 0);
            }
        }
        __syncthreads();  // all waves done reading hT; overlay zaT/zbT

        // stage Z: waves 0,1 -> Za (outs 0..63 bf16, [64][128B]); waves 2,3 -> Zb (outs 64..127 fp8)
        {
            unsigned char* zaT = smem;         // 8 KB
            unsigned char* zbT = smem + 8192;  // 4 KB
#pragma unroll
            for (int of = 0; of < 2; ++of)
#pragma unroll
                for (int nf = 0; nf < 4; ++nf) {
                    int node = nf * 16 + lr;
                    int out = w * 32 + of * 16 + rbase;
                    if (w < 2) {
                        uint2 pk;
                        pk.x = pack2bf(acc2[of][nf][0], acc2[of][nf][1]);
                        pk.y = pack2bf(acc2[of][nf][2], acc2[of][nf][3]);
                        unsigned int ob = (unsigned int)(out * 2);
                        *(uint2*)(zaT + node * 128 + (ob ^ ((unsigned int)(node & 7) << 4))) = pk;
                    } else {
                        unsigned int pk = fp8x4_enc(acc2[of][nf][0], acc2[of][nf][1],
                                                    acc2[of][nf][2], acc2[of][nf][3]);
                        unsigned int ob = (unsigned int)(out - 64);
                        *(unsigned int*)(zbT + node * 64 + (ob ^ ((unsigned int)(node & 3) << 4))) = pk;
                    }
                }
        }
        __syncthreads();

        // coalesced global stores (un-swizzling 16B chunks)
#pragma unroll
        for (int c = 0; c < 2; ++c) {  // Za: 512 x 16B
            int chunk = c * 256 + t;
            int row = chunk >> 3, cb = (chunk & 7) * 16;
            int grow = m0 + row;
            if (grow < n)
                *(uint4*)((unsigned char*)Za + (size_t)grow * 128 + cb) =
                    *(const uint4*)(smem + row * 128 + (cb ^ ((row & 7) << 4)));
        }
        {  // Zb: 256 x 16B
            int row = t >> 2, cb = (t & 3) * 16;
            int grow = m0 + row;
            if (grow < n)
                *(uint4*)(Zb8 + (size_t)grow * 64 + cb) =
                    *(const uint4*)(smem + 8192 + row * 64 + (cb ^ ((row & 3) << 4)));
        }
        __syncthreads();  // LDS reads of this tile's stores done before next tile's hT writes
    }
}

// ---------- agg2: out[v] = f32(Za[v]) + mean_u fp8(Zb[u]); quarter-wave per node ----------
// branch-free 8-deep loop (tail slots -> zero row n of Zb8).
__global__ __launch_bounds__(256) void agg2(const unsigned short* __restrict__ Za,
                                            const unsigned char* __restrict__ Zb8,
                                            const int* __restrict__ offs,
                                            const int* __restrict__ csr,
                                            float* __restrict__ out, int n) {
    int t = threadIdx.x;
    int q = t >> 4, cl = t & 15;
    int v = blockIdx.x * 16 + q;
    if (v >= n) return;
    int beg = offs[v], end = offs[v + 1];
    float a0 = 0.f, a1 = 0.f, a2 = 0.f, a3 = 0.f;
    for (int e = beg; e < end; e += 8) {
        int s[8];
#pragma unroll
        for (int k = 0; k < 8; ++k) {
            int idx = e + k;
            s[k] = (idx < end) ? csr[idx] : n;  // zero row for tail slots
        }
        unsigned int d[8];
#pragma unroll
        for (int k = 0; k < 8; ++k)
            d[k] = *(const unsigned int*)(Zb8 + (size_t)s[k] * 64 + cl * 4);
#pragma unroll
        for (int k = 0; k < 8; ++k) {
            float x, y, z, u2;
            fp8x4_dec(d[k], x, y, z, u2);
            a0 += x; a1 += y; a2 += z; a3 += u2;
        }
    }
    int deg = end - beg;
    float inv = 1.0f / (float)(deg > 0 ? deg : 1);
    uint2 uz = *(const uint2*)((const unsigned char*)Za + (size_t)v * 128 + cl * 8);
    float4 o;
    o.x = bf2f((unsigned short)uz.x) + a0 * inv;
    o.y = bf2f((unsigned short)(uz.x >> 16)) + a1 * inv;
    o.z = bf2f((unsigned short)uz.y) + a2 * inv;
    o.w = bf2f((unsigned short)(uz.y >> 16)) + a3 * inv;
    *(float4*)(out + (size_t)v * 64 + cl * 4) = o;
}

extern "C" void kernel_launch(void* const* d_in, const int* in_sizes, int n_in,
                              void* d_out, int out_size, void* d_ws, size_t ws_size,
                              hipStream_t stream) {
    const float* feat = (const float*)d_in[0];
    const int* esrc = (const int*)d_in[1];
    const int* edst = (const int*)d_in[2];
    const float* W0 = (const float*)d_in[3];  // [128, 256]
    const float* W1 = (const float*)d_in[4];  // [64, 256]
    float* out = (float*)d_out;

    int n = in_sizes[0] / 128;  // 100000
    int E = in_sizes[1];        // 1600000
    int NB = (n + 511) >> 9;    // 196 buckets

    char* ws = (char*)d_ws;
    size_t off = 0;
    auto alloc = [&](size_t bytes) -> void* {
        void* p = ws + off;
        off += (bytes + 255) & ~(size_t)255;
        return p;
    };
    int* offs = (int*)alloc((size_t)(n + 1) * 4);
    int* csr = (int*)alloc((size_t)(E + 8) * 4);  // +8 slack for speculative tail reads
    int* gcur = (int*)alloc((size_t)NB * 4);
    unsigned int* pairs = (unsigned int*)alloc((size_t)NB * BCAP * 4);
    unsigned short* Wb1 = (unsigned short*)alloc((size_t)128 * 256 * 2);
    unsigned short* Wb2 = (unsigned short*)alloc((size_t)128 * 128 * 2);
    unsigned short* Fb = (unsigned short*)alloc((size_t)n * 128 * 2);
    unsigned char* Ff8 = (unsigned char*)alloc((size_t)(n + 1) * 128);  // +1 zero pad row
    unsigned short* Mb = (unsigned short*)alloc((size_t)n * 128 * 2);
    unsigned short* Za = (unsigned short*)alloc((size_t)n * 64 * 2);
    unsigned char* Zb8 = (unsigned char*)alloc((size_t)(n + 1) * 64);   // +1 zero pad row

    int pblocks = (E + 4095) / 4096;  // 391
    int cblocks = 640;
    int nquad = n * 32;

    hipMemsetAsync(gcur, 0, (size_t)NB * 4, stream);
    megaA<<<pblocks + cblocks + 24, 256, 0, stream>>>(esrc, edst, gcur, pairs, E, NB,
                                                      feat, Fb, Ff8, nquad,
                                                      W0, Wb1, W1, Wb2, Zb8, n, pblocks, cblocks);
    build<<<NB, 256, 0, stream>>>(pairs, gcur, offs, csr, n, NB, E);

    agg1<<<(n + 15) / 16, 256, 0, stream>>>(Ff8, offs, csr, Mb, n);
    int ntiles = (n + 63) / 64;  // 1563
    int gblk = ntiles < 1024 ? ntiles : 1024;  // 4 blocks/CU (VGPR-allowed residency)
    fused_gemm<<<gblk, 256, 0, stream>>>(Fb, Mb, Wb1, Wb2, Za, Zb8, n, ntiles);
    agg2<<<(n + 15) / 16, 256, 0, stream>>>(Za, Zb8, offs, csr, out, n);
}